// Round 20
// baseline (1096.731 us; speedup 1.0000x reference)
//
#include <hip/hip_runtime.h>
#include <hip/hip_bf16.h>
#include <cstdint>
#include <cstddef>

// ---------------------------------------------------------------------------
// VQ-VAE forward (B=2048, L=100, D=64, K=64, CB=512) — v14.
// = v13 (round-19, proven 1090 us) with ONE change: xsq_k split into
// 2 half-column blocks per sample (256 threads, grid 2B) for co-residency
// (the 512-thread monolith only got 1 block/CU resident).
// Encoder: split-bf16 (hi+lo, 3 MFMAs) ~f32; decoder: plain bf16.
// Argmin exactness: margin 0.1 flag -> f64 full recompute of flagged rows.
// ---------------------------------------------------------------------------

typedef __attribute__((ext_vector_type(8))) short short8v;   // 8 bf16
typedef __attribute__((ext_vector_type(4))) float f32x4;

constexpr int B  = 2048;
constexpr int L  = 100;
constexpr int K  = 64;
constexpr int CB = 512;
#define MARGIN 0.1f

// ---- workspace layout (float-sized units) ----
constexpr size_t R0_OFF  = 0;          // A1P u32 -> G2 bf16
constexpr size_t R1_OFF  = 51380224;   // A2P u32 -> G1 bf16
constexpr size_t IDX_OFF = 84934656;   // 2048*49 ints
constexpr size_t CBN_OFF = 85035008;   // 64 norms
constexpr size_t CNT_OFF = 85035072;
constexpr size_t ACC_OFF = 85035088;
constexpr size_t WL_OFF  = 85035104;   // 100352 ints
constexpr size_t WB_OFF  = 85135456;   // bf16 weights (ushort units below)

// bf16 weight sub-offsets (ushort units), layout [4][OC][IC]
constexpr size_t EW1H=0,       EW1L=32768;
constexpr size_t EW2H=65536,   EW2L=196608;
constexpr size_t EW3H=327680;                   // [4][512][256] hi only
constexpr size_t DW2H=851968,  DW3H=983040;
constexpr size_t W3BH=1015808, W3BL=1081344;    // [4][64][256] hi/lo

constexpr size_t BW1_OFF  = WB_OFF + 573440;    // [4][64][256] f32
constexpr size_t DOTB_OFF = BW1_OFF + 65536;    // 64 f32

__device__ inline ushort bf16_hi(float f){ __hip_bfloat16 h=__float2bfloat16(f); return *(ushort*)&h; }
__device__ inline float  bf16_tof(ushort u){ __hip_bfloat16 h; *(ushort*)&h=u; return __bfloat162float(h); }

// ---------------------------------------------------------------------------
// weight prep: w[2,2,IC,OC] f32 -> Wt[kk][oc][ic] bf16 hi (+lo)
// ---------------------------------------------------------------------------
__device__ void wtrans(const float* __restrict__ w, int IC, int OC,
                       ushort* __restrict__ hi, ushort* __restrict__ lo,
                       int gid, int gsz)
{
    int tot = 4*IC*OC;
    for (int i = gid; i < tot; i += gsz) {
        int kk = i/(IC*OC), r = i - kk*(IC*OC), ic = r/OC, oc = r - ic*OC;
        float v = w[i];
        ushort h = bf16_hi(v);
        size_t dst = ((size_t)kk*OC + oc)*IC + ic;
        hi[dst] = h;
        if (lo) lo[dst] = bf16_hi(v - bf16_tof(h));
    }
}

__global__ __launch_bounds__(256)
void wprep_k(const float* e1, const float* e2, const float* e3,
             const float* d2, const float* d3, ushort* wb)
{
    int gid = blockIdx.x*256 + threadIdx.x, gsz = gridDim.x*256;
    wtrans(e1,  64, 128, wb+EW1H, wb+EW1L, gid, gsz);
    wtrans(e2, 128, 256, wb+EW2H, wb+EW2L, gid, gsz);
    wtrans(e3, 256, 512, wb+EW3H, nullptr, gid, gsz);
    wtrans(d2, 256, 128, wb+DW2H, nullptr, gid, gsz);
    wtrans(d3, 128,  64, wb+DW3H, nullptr, gid, gsz);
}

// ---------------------------------------------------------------------------
// W3B[kk][k][ic] = sum_cb e_w3[kk,ic,cb] * book[k,cb]  (hi/lo bf16)
// ---------------------------------------------------------------------------
__global__ __launch_bounds__(256)
void w3b_k(const float* __restrict__ e_w3, const float* __restrict__ book,
           ushort* __restrict__ wb)
{
    const int kk = blockIdx.x >> 6, k = blockIdx.x & 63, ic = threadIdx.x;
    const float4* wr = (const float4*)(e_w3 + ((size_t)(kk*256)+ic)*512);
    const float4* br = (const float4*)(book + (size_t)k*512);
    float s = 0.f;
    for (int c = 0; c < 128; ++c) {
        float4 a = wr[c], bb = br[c];
        s = fmaf(a.x,bb.x,fmaf(a.y,bb.y,fmaf(a.z,bb.z,fmaf(a.w,bb.w,s))));
    }
    size_t dst = ((size_t)(kk*64+k))*256 + ic;
    ushort h = bf16_hi(s);
    wb[W3BH+dst] = h;
    wb[W3BL+dst] = bf16_hi(s - bf16_tof(h));
}

// ---------------------------------------------------------------------------
// BW1[tap][k][oc] = sum_ic book[k,ic] * d_w1[tap,ic,oc]   (f32)
// ---------------------------------------------------------------------------
__global__ __launch_bounds__(256)
void bw1_k(const float* __restrict__ d_w1, const float* __restrict__ book,
           float* __restrict__ bw1)
{
    const int tap = blockIdx.x >> 6, k = blockIdx.x & 63, oc = threadIdx.x;
    const float* br = book + (size_t)k*512;
    const float* wr = d_w1 + (size_t)(tap*512)*256 + oc;
    float s = 0.f;
    for (int ic = 0; ic < 512; ++ic)
        s = fmaf(br[ic], wr[(size_t)ic*256], s);
    bw1[((size_t)(tap*64+k))*256 + oc] = s;
}

// ---------------------------------------------------------------------------
// prep: code norms, dotbias, zero accumulators + worklist count
// ---------------------------------------------------------------------------
__global__ __launch_bounds__(256)
void prep_k(const float* __restrict__ book, const float* __restrict__ e_b3,
            float* __restrict__ cbn, float* __restrict__ dotb,
            float* __restrict__ acc, int* __restrict__ cnt)
{
    const int t = threadIdx.x;
    if (t < 64) {
        const float* r = book + t * 512;
        float s = 0.f, d = 0.f;
        for (int c = 0; c < 512; ++c) { s = fmaf(r[c], r[c], s); d = fmaf(e_b3[c], r[c], d); }
        cbn[t] = s; dotb[t] = d;
    }
    if (t == 64 || t == 65) acc[t-64] = 0.f;
    if (t == 66) *cnt = 0;
}

// ---------------------------------------------------------------------------
// Per-sample MFMA conv (round-9/10 proven). Block = (SMP samples, oc-slice),
// XCD-remapped. DBUF: double-buffered LDS, 1 barrier/chunk, T14 prefetch,
// setprio around MFMA cluster.
// MODE 1: table gather+mask; 3: packed u32 hi|lo; 4: bf16.
// OUTFMT 0: f32; 1: packed u32; 2: bf16.  FUSE (SMP=1): vq_mean + loss1.
// ---------------------------------------------------------------------------
template<int IH,int IW,int IC,int OC,int PAD,int MODE,bool HASBN,bool SPLIT,
         int OCS,int ICC,int MT,int OUTFMT,bool FUSE,int SMP,bool DBUF>
__global__ __launch_bounds__(256)
void sconv_k(const uint* __restrict__ in_pk, const ushort* __restrict__ in_bf,
             const int* __restrict__ ids, const int* __restrict__ masks,
             const float* __restrict__ table,
             const ushort* __restrict__ wt_hi, const ushort* __restrict__ wt_lo,
             const float* __restrict__ bias, const float* __restrict__ gamma,
             const float* __restrict__ beta,
             float* __restrict__ out_f, uint* __restrict__ out_pk,
             ushort* __restrict__ out_bf, float* __restrict__ out_mean,
             float* __restrict__ acc_g)
{
    constexpr int OH=IH+2*PAD-1, OW=IW+2*PAD-1, NPOS=OH*OW, IHW=IH*IW;
    constexpr int OCB=OC/OCS, NPW=OCB/4, NT=NPW/16;
    constexpr int NCH=IC/ICC, KS=ICC/32;
    constexpr int PL=SPLIT?2:1;
    constexpr int NB=(DBUF && NCH>1)?2:1;
    constexpr int AROWS=IHW+1, RB=ICC*2;
    constexpr int C8=ICC/8;
    constexpr int NITEMS=SMP*IHW*C8;
    constexpr int SI=(NITEMS+255)/256;
    constexpr bool EXACT=(SI*256==NITEMS);
    constexpr int SPLB=AROWS*RB;
    constexpr int SAMB=PL*SPLB;
    constexpr int BUFB=SMP*SAMB;

    __shared__ ushort s_a[NB*SMP*PL*AROWS*ICC];
    char* sb=(char*)s_a;

    const int v=blockIdx.x, r8=v&7, iv=v>>3;
    const int b0 = (r8*(B/SMP/8) + iv/OCS)*SMP;
    const int sl = iv - (iv/OCS)*OCS;

    const int tid=threadIdx.x, lane=tid&63, wv=tid>>6;
    const int l15=lane&15, lq=lane>>4;
    const int n0=sl*OCB + wv*NPW;

    int arow[4][MT];
    #pragma unroll
    for(int kk=0;kk<4;++kk){
        const int ky=kk>>1, kx=kk&1;
        #pragma unroll
        for(int m=0;m<MT;++m){
            int p=m*16+l15;
            int py=p/OW, px=p-py*OW;
            int ty=py+ky-PAD, tx=px+kx-PAD;
            bool ok=(p<NPOS)&&((unsigned)ty<(unsigned)IH)&&((unsigned)tx<(unsigned)IW);
            arow[kk][m]= ok ? ty*IW+tx : IHW;
        }
    }

    f32x4 acc[SMP][MT][NT];
    #pragma unroll
    for(int s=0;s<SMP;++s)
        #pragma unroll
        for(int m=0;m<MT;++m)
            #pragma unroll
            for(int n=0;n<NT;++n) acc[s][m][n]=(f32x4)0.0f;

    uint4 r0[SI];
    uint4 r1[(MODE==1||MODE==3)?SI:1];
    float msk[(MODE==1)?SI:1];

    auto stage_load=[&](int c){
        const int ic0=c*ICC;
        #pragma unroll
        for(int t=0;t<SI;++t){
            int idx=tid+t*256;
            if(EXACT || idx<NITEMS){
                int row=idx/C8, g=idx-row*C8;
                int s=row/IHW, r=row-s*IHW;
                if constexpr(MODE==1){
                    int id=ids[(b0+s)*L+r];
                    msk[t]=(masks[(b0+s)*L+r]>=1)?1.f:0.f;
                    const float* src=table+(size_t)id*64+g*8;
                    r0[t]=*(const uint4*)src;
                    r1[t]=*(const uint4*)(src+4);
                } else if constexpr(MODE==3){
                    const uint* src=in_pk+((size_t)(b0+s)*IHW+r)*IC+ic0+g*8;
                    r0[t]=*(const uint4*)src;
                    r1[t]=*(const uint4*)(src+4);
                } else {
                    r0[t]=*(const uint4*)(in_bf+((size_t)(b0+s)*IHW+r)*IC+ic0+g*8);
                }
            }
        }
    };

    auto stage_write=[&](int bufb){
        #pragma unroll
        for(int t=0;t<SI;++t){
            int idx=tid+t*256;
            if(EXACT || idx<NITEMS){
                int row=idx/C8, g=idx-row*C8;
                int s=row/IHW, r=row-s*IHW;
                int boff=bufb + s*SAMB + r*RB + ((g^(r&7))<<4);
                if constexpr(MODE==1){
                    const float* f0=(const float*)&r0[t];
                    const float* f1=(const float*)&r1[t];
                    float vv[8]={f0[0]*msk[t],f0[1]*msk[t],f0[2]*msk[t],f0[3]*msk[t],
                                 f1[0]*msk[t],f1[1]*msk[t],f1[2]*msk[t],f1[3]*msk[t]};
                    ushort hh[8], ll[8];
                    #pragma unroll
                    for(int j=0;j<8;++j){ hh[j]=bf16_hi(vv[j]); ll[j]=bf16_hi(vv[j]-bf16_tof(hh[j])); }
                    *(uint4*)(sb+boff)=*(uint4*)hh;
                    *(uint4*)(sb+SPLB+boff)=*(uint4*)ll;
                } else if constexpr(MODE==3){
                    const uint* u0=(const uint*)&r0[t];
                    const uint* u1=(const uint*)&r1[t];
                    ushort hh[8], ll[8];
                    #pragma unroll
                    for(int j=0;j<4;++j){ hh[j]=(ushort)(u0[j]&0xffffu); ll[j]=(ushort)(u0[j]>>16); }
                    #pragma unroll
                    for(int j=0;j<4;++j){ hh[4+j]=(ushort)(u1[j]&0xffffu); ll[4+j]=(ushort)(u1[j]>>16); }
                    *(uint4*)(sb+boff)=*(uint4*)hh;
                    *(uint4*)(sb+SPLB+boff)=*(uint4*)ll;
                } else {
                    *(uint4*)(sb+boff)=r0[t];
                }
            }
        }
    };

    auto zero_rows=[&](){
        for(int z=tid; z<NB*SMP*PL*C8; z+=256){
            int nb=z/(SMP*PL*C8), rz=z-nb*(SMP*PL*C8);
            int s=rz/(PL*C8), rz2=rz-s*(PL*C8), pl=rz2/C8, g=rz2-pl*C8;
            *(uint4*)(sb + nb*BUFB + s*SAMB + pl*SPLB + IHW*RB + (g<<4)) = make_uint4(0,0,0,0);
        }
    };

    auto do_mfma=[&](int bufb, int c){
        const int ic0=c*ICC;
        __builtin_amdgcn_s_setprio(1);
        #pragma unroll
        for(int kk=0;kk<4;++kk){
            #pragma unroll
            for(int ks=0;ks<KS;++ks){
                short8v bhv[NT]; short8v blv[SPLIT?NT:1];
                #pragma unroll
                for(int n=0;n<NT;++n){
                    int col=n0+n*16+l15;
                    size_t widx=((size_t)kk*OC+col)*IC+ic0+ks*32+lq*8;
                    bhv[n]=*(const short8v*)(wt_hi+widx);
                    if constexpr(SPLIT) blv[n]=*(const short8v*)(wt_lo+widx);
                }
                #pragma unroll
                for(int s=0;s<SMP;++s){
                    const int sbase=bufb + s*SAMB;
                    #pragma unroll
                    for(int m=0;m<MT;++m){
                        int off=sbase + arow[kk][m]*RB + ((((ks<<2)|lq)^(arow[kk][m]&7))<<4);
                        short8v ah=*(const short8v*)(sb+off);
                        if constexpr(SPLIT){
                            short8v al=*(const short8v*)(sb+SPLB+off);
                            #pragma unroll
                            for(int n=0;n<NT;++n){
                                acc[s][m][n]=__builtin_amdgcn_mfma_f32_16x16x32_bf16(ah,bhv[n],acc[s][m][n],0,0,0);
                                acc[s][m][n]=__builtin_amdgcn_mfma_f32_16x16x32_bf16(ah,blv[n],acc[s][m][n],0,0,0);
                                acc[s][m][n]=__builtin_amdgcn_mfma_f32_16x16x32_bf16(al,bhv[n],acc[s][m][n],0,0,0);
                            }
                        } else {
                            #pragma unroll
                            for(int n=0;n<NT;++n)
                                acc[s][m][n]=__builtin_amdgcn_mfma_f32_16x16x32_bf16(ah,bhv[n],acc[s][m][n],0,0,0);
                        }
                    }
                }
            }
        }
        __builtin_amdgcn_s_setprio(0);
    };

    if constexpr(NB==1){
        stage_load(0);
        zero_rows();
        for(int c=0;c<NCH;++c){
            if(c) __syncthreads();
            stage_write(0);
            __syncthreads();
            if(c+1<NCH) stage_load(c+1);
            do_mfma(0,c);
        }
    } else {
        stage_load(0);
        stage_write(0);
        zero_rows();
        __syncthreads();
        for(int c=0;c<NCH;++c){
            if(c+1<NCH) stage_load(c+1);
            do_mfma((c&1)*BUFB,c);
            if(c+1<NCH){
                stage_write(((c+1)&1)*BUFB);
                __syncthreads();
            }
        }
    }

    const float rs=(float)(1.0/sqrt(1.0+1e-3));
    float lsum=0.f, colsum=0.f;
    #pragma unroll
    for(int s=0;s<SMP;++s){
        const int b=b0+s;
        #pragma unroll
        for(int n=0;n<NT;++n){
            int col=n0+n*16+l15;
            float bi=bias[col];
            float gsc=0.f, bt=0.f;
            if constexpr(HASBN){ gsc=gamma[col]*rs; bt=beta[col]; }
            #pragma unroll
            for(int m=0;m<MT;++m){
                #pragma unroll
                for(int j=0;j<4;++j){
                    int p=m*16+lq*4+j;
                    if(p<NPOS){
                        float vx=acc[s][m][n][j]+bi;
                        if constexpr(HASBN) vx=fmaxf(fmaf(vx,gsc,bt),0.f);
                        size_t g=(size_t)b*NPOS+p;
                        if constexpr(OUTFMT==0){
                            out_f[g*OC+col]=vx;
                        } else if constexpr(OUTFMT==1){
                            ushort h=bf16_hi(vx);
                            ushort lo=bf16_hi(vx-bf16_tof(h));
                            out_pk[g*OC+col]=(uint)h | ((uint)lo<<16);
                        } else {
                            out_bf[g*OC+col]=bf16_hi(vx);
                        }
                        if constexpr(FUSE){
                            int id=ids[b*L+p];
                            float mm=(masks[b*L+p]>=1)?1.f:0.f;
                            float h=table[(size_t)id*64+col]*mm;
                            float df=h-vx;
                            lsum=fmaf(df,df,lsum);
                            colsum+=vx;
                        }
                    }
                }
            }
        }
    }

    if constexpr(FUSE){
        const int b=b0;
        float mc=0.f;
        for(int l=lane;l<L;l+=64) mc += (masks[b*L+l]>=1)?1.f:0.f;
        #pragma unroll
        for(int off=32;off;off>>=1) mc+=__shfl_xor(mc,off);
        colsum += __shfl_xor(colsum,16);
        colsum += __shfl_xor(colsum,32);
        if(lq==0) out_mean[b*64 + n0 + l15] = colsum/mc;
        #pragma unroll
        for(int off=32;off;off>>=1) lsum+=__shfl_xor(lsum,off);
        __syncthreads();
        float* red=(float*)sb;
        if(lane==0) red[wv]=lsum;
        __syncthreads();
        if(tid==0) atomicAdd(acc_g+0, red[0]+red[1]+red[2]+red[3]);
    }
}

__device__ inline int xswz(int row, int sl){ return (sl ^ (row&31) ^ ((row>>3)&7)) << 4; }

// ---------------------------------------------------------------------------
// xsq2: Sum x^2, 2 half-column blocks per sample (256 thr, 4 waves each).
// Hi plane only (32 KB LDS). Each wave: 64 cols (2 passes x 2 col-chunks,
// each A-read feeds 2 MFMAs). Smaller blocks -> multi-block residency.
// ---------------------------------------------------------------------------
__global__ __launch_bounds__(256)
void xsq2_k(const uint* __restrict__ in_pk,
            const ushort* __restrict__ wx,                       // EW3H
            const float* __restrict__ xbias,                     // e_b3
            float* __restrict__ acc_g)
{
    constexpr int NPOS=49, OW=7, MT=4;
    constexpr int ROWB=512;

    __shared__ ushort s_a[64*256];          // hi plane only = 32 KB
    char* sb=(char*)s_a;

    const int v=blockIdx.x;
    const int sv=v>>1, half=v&1;
    const int b=(sv&7)*(B/8)+(sv>>3);
    const int tid=threadIdx.x, lane=tid&63, wv=tid>>6;   // wv in [0,4)
    const int l15=lane&15, lq=lane>>4;

    // stage hi plane, swizzled (2048 slots of 16B, 256 threads -> 8 iters)
    #pragma unroll
    for(int t=0;t<8;++t){
        int idx=tid+t*256;
        int row=idx>>5, sl=idx&31;
        const uint* src=in_pk+((size_t)b*64+row)*256+sl*8;
        uint4 u0=*(const uint4*)src, u1=*(const uint4*)(src+4);
        const uint* p0=(const uint*)&u0;
        const uint* p1=(const uint*)&u1;
        ushort hh[8];
        #pragma unroll
        for(int j=0;j<4;++j){ hh[j]=(ushort)(p0[j]&0xffffu); hh[4+j]=(ushort)(p1[j]&0xffffu); }
        *(uint4*)(sb+row*ROWB+xswz(row,sl))=*(uint4*)hh;
    }
    __syncthreads();

    int arow[4][MT];
    #pragma unroll
    for(int kk=0;kk<4;++kk){
        const int ky=kk>>1, kx=kk&1;
        #pragma unroll
        for(int m=0;m<MT;++m){
            int p=m*16+l15;
            int py=p/OW, px=p-py*OW;
            arow[kk][m]= (p<NPOS) ? (py+ky)*8+(px+kx) : 0;
        }
    }

    float xs=0.f;
    #pragma unroll
    for(int cc=0;cc<2;++cc){
        f32x4 accx[MT][2];
        #pragma unroll
        for(int m=0;m<MT;++m){ accx[m][0]=(f32x4)0.0f; accx[m][1]=(f32x4)0.0f; }
        const int col0=half*256+wv*64+cc*32+l15;
        __builtin_amdgcn_s_setprio(1);
        #pragma unroll
        for(int kk=0;kk<4;++kk){
            #pragma unroll
            for(int ks=0;ks<8;++ks){
                short8v bx0=*(const short8v*)(wx+((size_t)kk*512+col0)*256+ks*32+lq*8);
                short8v bx1=*(const short8v*)(wx+((size_t)kk*512+col0+16)*256+ks*32+lq*8);
                const int slb=ks*4+lq;
                #pragma unroll
                for(int m=0;m<MT;++m){
                    int r=arow[kk][m];
                    short8v ah=*(const short8v*)(sb+r*ROWB+xswz(r,slb));
                    accx[m][0]=__builtin_amdgcn_mfma_f32_16x16x32_bf16(ah,bx0,accx[m][0],0,0,0);
                    accx[m][1]=__builtin_amdgcn_mfma_f32_16x16x32_bf16(ah,bx1,accx[m][1],0,0,0);
                }
            }
        }
        __builtin_amdgcn_s_setprio(0);
        #pragma unroll
        for(int n=0;n<2;++n){
            const float bi=xbias[col0+n*16];
            #pragma unroll
            for(int m=0;m<MT;++m){
                #pragma unroll
                for(int j=0;j<4;++j){
                    int p=m*16+lq*4+j;
                    if(p<NPOS){ float vv=accx[m][n][j]+bi; xs=fmaf(vv,vv,xs); }
                }
            }
        }
    }
    #pragma unroll
    for(int off=32;off;off>>=1) xs+=__shfl_xor(xs,off);

    __syncthreads();
    float* f=(float*)sb;
    if(lane==0) f[wv]=xs;
    __syncthreads();
    if(tid==0) atomicAdd(acc_g+1, f[0]+f[1]+f[2]+f[3]);
}

// ---------------------------------------------------------------------------
// dot: folded-codebook dots + argmin. Hi+lo (64 KB LDS), 512 threads, K-split.
// ---------------------------------------------------------------------------
__global__ __launch_bounds__(512)
void dot_k(const uint* __restrict__ in_pk,
           const ushort* __restrict__ w3bh, const ushort* __restrict__ w3bl,
           const float* __restrict__ cbn, const float* __restrict__ dotb,
           int* __restrict__ qidx, float* __restrict__ acc_g,
           int* __restrict__ cnt, int* __restrict__ wl)
{
    constexpr int NPOS=49, OW=7, MT=4;
    constexpr int ROWB=512;
    constexpr int PLB=64*ROWB;

    __shared__ ushort s_a[2*64*256];        // hi + lo = 64 KB
    char* sb=(char*)s_a;

    const int v=blockIdx.x;
    const int b=(v&7)*(B/8)+(v>>3);
    const int tid=threadIdx.x, lane=tid&63, wv=tid>>6;
    const int l15=lane&15, lq=lane>>4;

    #pragma unroll
    for(int t=0;t<4;++t){
        int idx=tid+t*512;
        int row=idx>>5, sl=idx&31;
        const uint* src=in_pk+((size_t)b*64+row)*256+sl*8;
        uint4 u0=*(const uint4*)src, u1=*(const uint4*)(src+4);
        const uint* p0=(const uint*)&u0;
        const uint* p1=(const uint*)&u1;
        ushort hh[8], ll[8];
        #pragma unroll
        for(int j=0;j<4;++j){ hh[j]=(ushort)(p0[j]&0xffffu); ll[j]=(ushort)(p0[j]>>16); }
        #pragma unroll
        for(int j=0;j<4;++j){ hh[4+j]=(ushort)(p1[j]&0xffffu); ll[4+j]=(ushort)(p1[j]>>16); }
        int boff=row*ROWB+xswz(row,sl);
        *(uint4*)(sb+boff)=*(uint4*)hh;
        *(uint4*)(sb+PLB+boff)=*(uint4*)ll;
    }
    __syncthreads();

    int arow[4][MT];
    #pragma unroll
    for(int kk=0;kk<4;++kk){
        const int ky=kk>>1, kx=kk&1;
        #pragma unroll
        for(int m=0;m<MT;++m){
            int p=m*16+l15;
            int py=p/OW, px=p-py*OW;
            arow[kk][m]= (p<NPOS) ? (py+ky)*8+(px+kx) : 0;
        }
    }

    const int cold=(wv&3)*16+l15;
    const int ks0=(wv>>2)*4;
    f32x4 accd[MT];
    #pragma unroll
    for(int m=0;m<MT;++m) accd[m]=(f32x4)0.0f;

    __builtin_amdgcn_s_setprio(1);
    #pragma unroll
    for(int kk=0;kk<4;++kk){
        #pragma unroll
        for(int kq2=0;kq2<4;++kq2){
            const int ks=ks0+kq2;
            size_t wdx=((size_t)kk*64+cold)*256+ks*32+lq*8;
            short8v bdh=*(const short8v*)(w3bh+wdx);
            short8v bdl=*(const short8v*)(w3bl+wdx);
            const int slb=ks*4+lq;
            #pragma unroll
            for(int m=0;m<MT;++m){
                int r=arow[kk][m];
                int off=r*ROWB+xswz(r,slb);
                short8v ah=*(const short8v*)(sb+off);
                short8v al=*(const short8v*)(sb+PLB+off);
                accd[m]=__builtin_amdgcn_mfma_f32_16x16x32_bf16(ah,bdh,accd[m],0,0,0);
                accd[m]=__builtin_amdgcn_mfma_f32_16x16x32_bf16(ah,bdl,accd[m],0,0,0);
                accd[m]=__builtin_amdgcn_mfma_f32_16x16x32_bf16(al,bdh,accd[m],0,0,0);
            }
        }
    }
    __builtin_amdgcn_s_setprio(0);

    __syncthreads();
    float* f=(float*)sb;
    if(wv>=4){
        float* dst=f+((wv-4)*64+lane)*16;
        #pragma unroll
        for(int m=0;m<MT;++m){
            #pragma unroll
            for(int j=0;j<4;++j) dst[m*4+j]=accd[m][j];
        }
    }
    __syncthreads();

    float* sd1=f+4096;
    int*   sk =(int*)(f+4096+256);
    float* sd2=f+4096+512;
    if(wv<4){
        const float* srcp=f+(wv*64+lane)*16;
        float cb=cbn[cold], db=dotb[cold];
        #pragma unroll
        for(int m=0;m<MT;++m){
            #pragma unroll
            for(int j=0;j<4;++j){
                int p=m*16+lq*4+j;
                float dtot=accd[m][j]+srcp[m*4+j];
                float d1=cb-2.f*(dtot+db);
                int   k1=cold;
                float d2=3.4e38f;
                #pragma unroll
                for(int off=1;off<16;off<<=1){
                    float od1=__shfl_xor(d1,off);
                    int   ok1=__shfl_xor(k1,off);
                    float od2=__shfl_xor(d2,off);
                    if(od1<d1 || (od1==d1 && ok1<k1)){ d2=fminf(d1,od2); d1=od1; k1=ok1; }
                    else                              { d2=fminf(d2,od1); }
                }
                if(l15==0 && p<NPOS){ sd1[p*4+wv]=d1; sk[p*4+wv]=k1; sd2[p*4+wv]=d2; }
            }
        }
    }
    __syncthreads();

    {
        float lsum=0.f;
        if(tid<NPOS){
            float d1=sd1[tid*4+0]; int k1=sk[tid*4+0]; float d2=sd2[tid*4+0];
            #pragma unroll
            for(int w=1;w<4;++w){
                float D1=sd1[tid*4+w]; int K1=sk[tid*4+w]; float D2=sd2[tid*4+w];
                if(D1<d1){ d2=fminf(d1,D2); d1=D1; k1=K1; }
                else     { d2=fminf(d2,D1); }
            }
            qidx[b*49+tid]=k1;
            if(d2-d1<=MARGIN){ int t=atomicAdd(cnt,1); wl[t]=b*49+tid; }
            lsum=d1;
        }
        if(tid<64){
            #pragma unroll
            for(int off=32;off;off>>=1) lsum+=__shfl_xor(lsum,off);
            if(tid==0) atomicAdd(acc_g+1, lsum);
        }
    }
}

// ---------------------------------------------------------------------------
// deconv1 as gather-sum over BW1.
// ---------------------------------------------------------------------------
__global__ __launch_bounds__(256)
void dgather_k(const int* __restrict__ qidx, const float* __restrict__ bw1,
               const float* __restrict__ b1, const float* __restrict__ g1s,
               const float* __restrict__ be1, ushort* __restrict__ G1)
{
    const int b=blockIdx.x, tid=threadIdx.x;
    const int pg=tid>>2, og=(tid&3)*64;
    const int py=pg>>3, px=pg&7;

    float a[64];
    #pragma unroll
    for(int j=0;j<64;++j) a[j]=0.f;

    #pragma unroll
    for(int tap=0;tap<4;++tap){
        int iy=py+(tap>>1)-1, ix=px+(tap&1)-1;
        if((unsigned)iy<7u && (unsigned)ix<7u){
            int kq=qidx[b*49+iy*7+ix];
            const float4* src=(const float4*)(bw1+((size_t)(tap*64+kq))*256+og);
            #pragma unroll
            for(int j=0;j<16;++j){
                float4 vv=src[j];
                a[4*j+0]+=vv.x; a[4*j+1]+=vv.y; a[4*j+2]+=vv.z; a[4*j+3]+=vv.w;
            }
        }
    }
    const float rs=(float)(1.0/sqrt(1.0+1e-3));
    #pragma unroll
    for(int j=0;j<64;++j){
        int col=og+j;
        float vv=a[j]+b1[col];
        vv=fmaxf(fmaf(vv, g1s[col]*rs, be1[col]), 0.f);
        G1[((size_t)b*64+pg)*256+col]=bf16_hi(vv);
    }
}

// ---------------------------------------------------------------------------
// f64 re-verification of flagged rows (full receptive field from scratch).
// Round-16 byte-identical body; grid 2048.
// ---------------------------------------------------------------------------
__global__ __launch_bounds__(256)
void recompute_k(const int* __restrict__ wl, const int* __restrict__ cnt,
                 const int* __restrict__ ids, const int* __restrict__ masks,
                 const float* __restrict__ table, const float* __restrict__ book,
                 const float* __restrict__ e_w1, const float* __restrict__ e_b1,
                 const float* __restrict__ e_g1, const float* __restrict__ e_be1,
                 const float* __restrict__ e_w2, const float* __restrict__ e_b2,
                 const float* __restrict__ e_g2, const float* __restrict__ e_be2,
                 const float* __restrict__ e_w3, const float* __restrict__ e_b3,
                 int* __restrict__ qidx)
{
    __shared__ double s_h[16*64];
    __shared__ double s_a1[9*128];
    __shared__ double s_a2[4*256];
    __shared__ double s_x[512];
    __shared__ double s_d[256];

    const int tid = threadIdx.x;
    const double rs = 1.0 / sqrt(1.0 + 1e-3);
    const int n = *cnt;

    for (int wi = blockIdx.x; wi < n; wi += gridDim.x) {
        const int row = wl[wi];
        const int b = row / 49, p = row % 49;
        const int py = p / 7, px = p % 7;

        for (int i = tid; i < 16*64; i += 256) {
            int cell = i >> 6, d = i & 63;
            int l = (py + (cell >> 2)) * 10 + (px + (cell & 3));
            int id = ids[b*100 + l];
            double m = (masks[b*100 + l] >= 1) ? 1.0 : 0.0;
            s_h[i] = (double)table[(size_t)id*64 + d] * m;
        }
        __syncthreads();

        for (int i = tid; i < 9*128; i += 256) {
            int cell = i >> 7, oc = i & 127;
            int ry = cell / 3, rx = cell % 3;
            double s = 0.0;
            #pragma unroll
            for (int kk = 0; kk < 4; ++kk) {
                int icell = (ry + (kk>>1))*4 + (rx + (kk&1));
                const double* hh = s_h + icell*64;
                const float* ww = e_w1 + (kk*64)*128 + oc;
                for (int ic = 0; ic < 64; ++ic)
                    s = fma(hh[ic], (double)ww[ic*128], s);
            }
            s += (double)e_b1[oc];
            s = s * ((double)e_g1[oc] * rs) + (double)e_be1[oc];
            s_a1[i] = s > 0.0 ? s : 0.0;
        }
        __syncthreads();

        for (int i = tid; i < 4*256; i += 256) {
            int cell = i >> 8, oc = i & 255;
            int qy = cell >> 1, qx = cell & 1;
            double s = 0.0;
            #pragma unroll
            for (int kk = 0; kk < 4; ++kk) {
                int icell = (qy + (kk>>1))*3 + (qx + (kk&1));
                const double* aa = s_a1 + icell*128;
                const float* ww = e_w2 + (kk*128)*256 + oc;
                for (int ic = 0; ic < 128; ++ic)
                    s = fma(aa[ic], (double)ww[ic*256], s);
            }
            s += (double)e_b2[oc];
            s = s * ((double)e_g2[oc] * rs) + (double)e_be2[oc];
            s_a2[i] = s > 0.0 ? s : 0.0;
        }
        __syncthreads();

        for (int i = tid; i < 512; i += 256) {
            double s = 0.0;
            #pragma unroll
            for (int kk = 0; kk < 4; ++kk) {
                const double* aa = s_a2 + kk*256;
                const float* ww = e_w3 + (kk*256)*512 + i;
                for (int ic = 0; ic < 256; ++ic)
                    s = fma(aa[ic], (double)ww[ic*512], s);
            }
            s_x[i] = s + (double)e_b3[i];
        }
        __syncthreads();

        {
            int k = tid & 63, seg = tid >> 6;
            const float* cr = book + k*512 + seg*128;
            const double* xr = s_x + seg*128;
            double s = 0.0;
            for (int c = 0; c < 128; ++c) {
                double dd = xr[c] - (double)cr[c];
                s = fma(dd, dd, s);
            }
            s_d[seg*64 + k] = s;
        }
        __syncthreads();

        if (tid < 64) {
            double dv = s_d[tid] + s_d[64+tid] + s_d[128+tid] + s_d[192+tid];
            int kk2 = tid;
            #pragma unroll
            for (int off = 32; off > 0; off >>= 1) {
                double od = __shfl_xor(dv, off);
                int    ok = __shfl_xor(kk2, off);
                if (od < dv || (od == dv && ok < kk2)) { dv = od; kk2 = ok; }
            }
            if (tid == 0) qidx[row] = kk2;
        }
        __syncthreads();
    }
}

__global__ void loss_k(const float* __restrict__ acc, float* __restrict__ out_loss)
{
    float l1 = acc[0] / 13107200.f;
    float l2 = acc[1] / 51380224.f;
    out_loss[0] = l1 + l2 + 0.25f * l2;
}

// ---------------------------------------------------------------------------
extern "C" void kernel_launch(void* const* d_in, const int* in_sizes, int n_in,
                              void* d_out, int out_size, void* d_ws, size_t ws_size,
                              hipStream_t stream)
{
    const int*   ids   = (const int*)d_in[0];
    const int*   masks = (const int*)d_in[1];
    const float* table = (const float*)d_in[2];
    const float* book  = (const float*)d_in[3];
    const float* e_w1  = (const float*)d_in[4];
    const float* e_b1  = (const float*)d_in[5];
    const float* e_g1  = (const float*)d_in[6];
    const float* e_be1 = (const float*)d_in[7];
    const float* e_w2  = (const float*)d_in[8];
    const float* e_b2  = (const float*)d_in[9];
    const float* e_g2  = (const float*)d_in[10];
    const float* e_be2 = (const float*)d_in[11];
    const float* e_w3  = (const float*)d_in[12];
    const float* e_b3  = (const float*)d_in[13];
    const float* d_w1  = (const float*)d_in[14];
    const float* d_b1  = (const float*)d_in[15];
    const float* d_g1  = (const float*)d_in[16];
    const float* d_be1 = (const float*)d_in[17];
    const float* d_w2  = (const float*)d_in[18];
    const float* d_b2  = (const float*)d_in[19];
    const float* d_g2  = (const float*)d_in[20];
    const float* d_be2 = (const float*)d_in[21];
    const float* d_w3  = (const float*)d_in[22];
    const float* d_b3  = (const float*)d_in[23];

    float*  ws  = (float*)d_ws;
    uint*   A1P = (uint*)(ws + R0_OFF);   // [B*81*128] u32 hi|lo
    uint*   A2P = (uint*)(ws + R1_OFF);   // [B*64*256] u32 hi|lo
    ushort* G1  = (ushort*)(ws + R1_OFF); // [B*64*256] bf16 (after dot/xsq)
    ushort* G2  = (ushort*)(ws + R0_OFF); // [B*81*128] bf16 (after conv2)
    int*    IDX = (int*)(ws + IDX_OFF);
    float*  CBN = ws + CBN_OFF;
    int*    CNT = (int*)(ws + CNT_OFF);
    float*  ACC = ws + ACC_OFF;
    int*    WL  = (int*)(ws + WL_OFF);
    ushort* WB  = (ushort*)(ws + WB_OFF);
    float*  BW1 = ws + BW1_OFF;
    float*  DOTB= ws + DOTB_OFF;

    float* out_mean = (float*)d_out;
    float* out_vqx  = (float*)d_out + (size_t)B * 64;
    float* out_loss = (float*)d_out + (size_t)B * 64 + (size_t)B * L * 64;

    prep_k<<<1, 256, 0, stream>>>(book, e_b3, CBN, DOTB, ACC, CNT);
    wprep_k<<<512, 256, 0, stream>>>(e_w1, e_w2, e_w3, d_w2, d_w3, WB);
    w3b_k<<<256, 256, 0, stream>>>(e_w3, book, WB);
    bw1_k<<<256, 256, 0, stream>>>(d_w1, book, BW1);

    // encoder (split-bf16) — round-10 configs
    sconv_k<10,10, 64,128,0,1,true ,true ,1, 64,6,1,false,1,true ><<<B,   256,0,stream>>>(
        nullptr, nullptr, ids, masks, table,
        WB+EW1H, WB+EW1L, e_b1, e_g1, e_be1, nullptr, A1P, nullptr, nullptr, nullptr);
    sconv_k< 9, 9,128,256,0,3,true ,true ,2, 64,4,1,false,1,true ><<<B*2, 256,0,stream>>>(
        A1P, nullptr, nullptr, nullptr, nullptr,
        WB+EW2H, WB+EW2L, e_b2, e_g2, e_be2, nullptr, A2P, nullptr, nullptr, nullptr);

    // Sum x^2 (2 half-col blocks/sample) + folded-codebook dots/argmin
    xsq2_k<<<2*B, 256, 0, stream>>>(A2P, WB+EW3H, e_b3, ACC);
    dot_k<<<B, 512, 0, stream>>>(A2P, WB+W3BH, WB+W3BL, CBN, DOTB, IDX, ACC, CNT, WL);

    // f64 re-verify flagged rows (round-16 kernel, grid 2048)
    recompute_k<<<2048, 256, 0, stream>>>(WL, CNT, ids, masks, table, book,
                                          e_w1, e_b1, e_g1, e_be1,
                                          e_w2, e_b2, e_g2, e_be2,
                                          e_w3, e_b3, IDX);

    // decoder: deconv1 = gather-sum; deconv2/3 = bf16 MFMA convs (round-10)
    dgather_k<<<B, 256, 0, stream>>>(IDX, BW1, d_b1, d_g1, d_be1, G1);
    sconv_k< 8, 8,256,128,1,4,true ,false,1, 64,6,2,false,1,true ><<<B,   256,0,stream>>>(
        nullptr, G1, nullptr, nullptr, nullptr,
        WB+DW2H, nullptr, d_b2, d_g2, d_be2, nullptr, nullptr, G2, nullptr, nullptr);
    sconv_k< 9, 9,128, 64,1,4,false,false,1, 64,7,0,true ,1,true ><<<B,   256,0,stream>>>(
        nullptr, G2, ids, masks, table,
        WB+DW3H, nullptr, d_b3, nullptr, nullptr, out_vqx, nullptr, nullptr, out_mean, ACC);

    loss_k<<<1, 1, 0, stream>>>(ACC, out_loss);
}

// Round 21
// 1090.224 us; speedup vs baseline: 1.0060x; 1.0060x over previous
//
#include <hip/hip_runtime.h>
#include <hip/hip_bf16.h>
#include <cstdint>
#include <cstddef>

// ---------------------------------------------------------------------------
// VQ-VAE forward (B=2048, L=100, D=64, K=64, CB=512) — v15.
// = v13 (round-19, proven 1090 us best) BYTE-IDENTICAL kernels; sole change:
// recompute_k grid 2048 -> 8192 (launch config only).
// Encoder: split-bf16 (hi+lo, 3 MFMAs) ~f32; decoder: plain bf16.
// Argmin exactness: margin 0.1 flag -> f64 full recompute of flagged rows.
// ---------------------------------------------------------------------------

typedef __attribute__((ext_vector_type(8))) short short8v;   // 8 bf16
typedef __attribute__((ext_vector_type(4))) float f32x4;

constexpr int B  = 2048;
constexpr int L  = 100;
constexpr int K  = 64;
constexpr int CB = 512;
#define MARGIN 0.1f

// ---- workspace layout (float-sized units) ----
constexpr size_t R0_OFF  = 0;          // A1P u32 -> G2 bf16
constexpr size_t R1_OFF  = 51380224;   // A2P u32 -> G1 bf16
constexpr size_t IDX_OFF = 84934656;   // 2048*49 ints
constexpr size_t CBN_OFF = 85035008;   // 64 norms
constexpr size_t CNT_OFF = 85035072;
constexpr size_t ACC_OFF = 85035088;
constexpr size_t WL_OFF  = 85035104;   // 100352 ints
constexpr size_t WB_OFF  = 85135456;   // bf16 weights (ushort units below)

// bf16 weight sub-offsets (ushort units), layout [4][OC][IC]
constexpr size_t EW1H=0,       EW1L=32768;
constexpr size_t EW2H=65536,   EW2L=196608;
constexpr size_t EW3H=327680;                   // [4][512][256] hi only
constexpr size_t DW2H=851968,  DW3H=983040;
constexpr size_t W3BH=1015808, W3BL=1081344;    // [4][64][256] hi/lo

constexpr size_t BW1_OFF  = WB_OFF + 573440;    // [4][64][256] f32
constexpr size_t DOTB_OFF = BW1_OFF + 65536;    // 64 f32

__device__ inline ushort bf16_hi(float f){ __hip_bfloat16 h=__float2bfloat16(f); return *(ushort*)&h; }
__device__ inline float  bf16_tof(ushort u){ __hip_bfloat16 h; *(ushort*)&h=u; return __bfloat162float(h); }

// ---------------------------------------------------------------------------
// weight prep: w[2,2,IC,OC] f32 -> Wt[kk][oc][ic] bf16 hi (+lo)
// ---------------------------------------------------------------------------
__device__ void wtrans(const float* __restrict__ w, int IC, int OC,
                       ushort* __restrict__ hi, ushort* __restrict__ lo,
                       int gid, int gsz)
{
    int tot = 4*IC*OC;
    for (int i = gid; i < tot; i += gsz) {
        int kk = i/(IC*OC), r = i - kk*(IC*OC), ic = r/OC, oc = r - ic*OC;
        float v = w[i];
        ushort h = bf16_hi(v);
        size_t dst = ((size_t)kk*OC + oc)*IC + ic;
        hi[dst] = h;
        if (lo) lo[dst] = bf16_hi(v - bf16_tof(h));
    }
}

__global__ __launch_bounds__(256)
void wprep_k(const float* e1, const float* e2, const float* e3,
             const float* d2, const float* d3, ushort* wb)
{
    int gid = blockIdx.x*256 + threadIdx.x, gsz = gridDim.x*256;
    wtrans(e1,  64, 128, wb+EW1H, wb+EW1L, gid, gsz);
    wtrans(e2, 128, 256, wb+EW2H, wb+EW2L, gid, gsz);
    wtrans(e3, 256, 512, wb+EW3H, nullptr, gid, gsz);
    wtrans(d2, 256, 128, wb+DW2H, nullptr, gid, gsz);
    wtrans(d3, 128,  64, wb+DW3H, nullptr, gid, gsz);
}

// ---------------------------------------------------------------------------
// W3B[kk][k][ic] = sum_cb e_w3[kk,ic,cb] * book[k,cb]  (hi/lo bf16)
// ---------------------------------------------------------------------------
__global__ __launch_bounds__(256)
void w3b_k(const float* __restrict__ e_w3, const float* __restrict__ book,
           ushort* __restrict__ wb)
{
    const int kk = blockIdx.x >> 6, k = blockIdx.x & 63, ic = threadIdx.x;
    const float4* wr = (const float4*)(e_w3 + ((size_t)(kk*256)+ic)*512);
    const float4* br = (const float4*)(book + (size_t)k*512);
    float s = 0.f;
    for (int c = 0; c < 128; ++c) {
        float4 a = wr[c], bb = br[c];
        s = fmaf(a.x,bb.x,fmaf(a.y,bb.y,fmaf(a.z,bb.z,fmaf(a.w,bb.w,s))));
    }
    size_t dst = ((size_t)(kk*64+k))*256 + ic;
    ushort h = bf16_hi(s);
    wb[W3BH+dst] = h;
    wb[W3BL+dst] = bf16_hi(s - bf16_tof(h));
}

// ---------------------------------------------------------------------------
// BW1[tap][k][oc] = sum_ic book[k,ic] * d_w1[tap,ic,oc]   (f32)
// ---------------------------------------------------------------------------
__global__ __launch_bounds__(256)
void bw1_k(const float* __restrict__ d_w1, const float* __restrict__ book,
           float* __restrict__ bw1)
{
    const int tap = blockIdx.x >> 6, k = blockIdx.x & 63, oc = threadIdx.x;
    const float* br = book + (size_t)k*512;
    const float* wr = d_w1 + (size_t)(tap*512)*256 + oc;
    float s = 0.f;
    for (int ic = 0; ic < 512; ++ic)
        s = fmaf(br[ic], wr[(size_t)ic*256], s);
    bw1[((size_t)(tap*64+k))*256 + oc] = s;
}

// ---------------------------------------------------------------------------
// prep: code norms, dotbias, zero accumulators + worklist count
// ---------------------------------------------------------------------------
__global__ __launch_bounds__(256)
void prep_k(const float* __restrict__ book, const float* __restrict__ e_b3,
            float* __restrict__ cbn, float* __restrict__ dotb,
            float* __restrict__ acc, int* __restrict__ cnt)
{
    const int t = threadIdx.x;
    if (t < 64) {
        const float* r = book + t * 512;
        float s = 0.f, d = 0.f;
        for (int c = 0; c < 512; ++c) { s = fmaf(r[c], r[c], s); d = fmaf(e_b3[c], r[c], d); }
        cbn[t] = s; dotb[t] = d;
    }
    if (t == 64 || t == 65) acc[t-64] = 0.f;
    if (t == 66) *cnt = 0;
}

// ---------------------------------------------------------------------------
// Per-sample MFMA conv (round-9/10 proven). Block = (SMP samples, oc-slice),
// XCD-remapped. DBUF: double-buffered LDS, 1 barrier/chunk, T14 prefetch,
// setprio around MFMA cluster.
// MODE 1: table gather+mask; 3: packed u32 hi|lo; 4: bf16.
// OUTFMT 0: f32; 1: packed u32; 2: bf16.  FUSE (SMP=1): vq_mean + loss1.
// ---------------------------------------------------------------------------
template<int IH,int IW,int IC,int OC,int PAD,int MODE,bool HASBN,bool SPLIT,
         int OCS,int ICC,int MT,int OUTFMT,bool FUSE,int SMP,bool DBUF>
__global__ __launch_bounds__(256)
void sconv_k(const uint* __restrict__ in_pk, const ushort* __restrict__ in_bf,
             const int* __restrict__ ids, const int* __restrict__ masks,
             const float* __restrict__ table,
             const ushort* __restrict__ wt_hi, const ushort* __restrict__ wt_lo,
             const float* __restrict__ bias, const float* __restrict__ gamma,
             const float* __restrict__ beta,
             float* __restrict__ out_f, uint* __restrict__ out_pk,
             ushort* __restrict__ out_bf, float* __restrict__ out_mean,
             float* __restrict__ acc_g)
{
    constexpr int OH=IH+2*PAD-1, OW=IW+2*PAD-1, NPOS=OH*OW, IHW=IH*IW;
    constexpr int OCB=OC/OCS, NPW=OCB/4, NT=NPW/16;
    constexpr int NCH=IC/ICC, KS=ICC/32;
    constexpr int PL=SPLIT?2:1;
    constexpr int NB=(DBUF && NCH>1)?2:1;
    constexpr int AROWS=IHW+1, RB=ICC*2;
    constexpr int C8=ICC/8;
    constexpr int NITEMS=SMP*IHW*C8;
    constexpr int SI=(NITEMS+255)/256;
    constexpr bool EXACT=(SI*256==NITEMS);
    constexpr int SPLB=AROWS*RB;
    constexpr int SAMB=PL*SPLB;
    constexpr int BUFB=SMP*SAMB;

    __shared__ ushort s_a[NB*SMP*PL*AROWS*ICC];
    char* sb=(char*)s_a;

    const int v=blockIdx.x, r8=v&7, iv=v>>3;
    const int b0 = (r8*(B/SMP/8) + iv/OCS)*SMP;
    const int sl = iv - (iv/OCS)*OCS;

    const int tid=threadIdx.x, lane=tid&63, wv=tid>>6;
    const int l15=lane&15, lq=lane>>4;
    const int n0=sl*OCB + wv*NPW;

    int arow[4][MT];
    #pragma unroll
    for(int kk=0;kk<4;++kk){
        const int ky=kk>>1, kx=kk&1;
        #pragma unroll
        for(int m=0;m<MT;++m){
            int p=m*16+l15;
            int py=p/OW, px=p-py*OW;
            int ty=py+ky-PAD, tx=px+kx-PAD;
            bool ok=(p<NPOS)&&((unsigned)ty<(unsigned)IH)&&((unsigned)tx<(unsigned)IW);
            arow[kk][m]= ok ? ty*IW+tx : IHW;
        }
    }

    f32x4 acc[SMP][MT][NT];
    #pragma unroll
    for(int s=0;s<SMP;++s)
        #pragma unroll
        for(int m=0;m<MT;++m)
            #pragma unroll
            for(int n=0;n<NT;++n) acc[s][m][n]=(f32x4)0.0f;

    uint4 r0[SI];
    uint4 r1[(MODE==1||MODE==3)?SI:1];
    float msk[(MODE==1)?SI:1];

    auto stage_load=[&](int c){
        const int ic0=c*ICC;
        #pragma unroll
        for(int t=0;t<SI;++t){
            int idx=tid+t*256;
            if(EXACT || idx<NITEMS){
                int row=idx/C8, g=idx-row*C8;
                int s=row/IHW, r=row-s*IHW;
                if constexpr(MODE==1){
                    int id=ids[(b0+s)*L+r];
                    msk[t]=(masks[(b0+s)*L+r]>=1)?1.f:0.f;
                    const float* src=table+(size_t)id*64+g*8;
                    r0[t]=*(const uint4*)src;
                    r1[t]=*(const uint4*)(src+4);
                } else if constexpr(MODE==3){
                    const uint* src=in_pk+((size_t)(b0+s)*IHW+r)*IC+ic0+g*8;
                    r0[t]=*(const uint4*)src;
                    r1[t]=*(const uint4*)(src+4);
                } else {
                    r0[t]=*(const uint4*)(in_bf+((size_t)(b0+s)*IHW+r)*IC+ic0+g*8);
                }
            }
        }
    };

    auto stage_write=[&](int bufb){
        #pragma unroll
        for(int t=0;t<SI;++t){
            int idx=tid+t*256;
            if(EXACT || idx<NITEMS){
                int row=idx/C8, g=idx-row*C8;
                int s=row/IHW, r=row-s*IHW;
                int boff=bufb + s*SAMB + r*RB + ((g^(r&7))<<4);
                if constexpr(MODE==1){
                    const float* f0=(const float*)&r0[t];
                    const float* f1=(const float*)&r1[t];
                    float vv[8]={f0[0]*msk[t],f0[1]*msk[t],f0[2]*msk[t],f0[3]*msk[t],
                                 f1[0]*msk[t],f1[1]*msk[t],f1[2]*msk[t],f1[3]*msk[t]};
                    ushort hh[8], ll[8];
                    #pragma unroll
                    for(int j=0;j<8;++j){ hh[j]=bf16_hi(vv[j]); ll[j]=bf16_hi(vv[j]-bf16_tof(hh[j])); }
                    *(uint4*)(sb+boff)=*(uint4*)hh;
                    *(uint4*)(sb+SPLB+boff)=*(uint4*)ll;
                } else if constexpr(MODE==3){
                    const uint* u0=(const uint*)&r0[t];
                    const uint* u1=(const uint*)&r1[t];
                    ushort hh[8], ll[8];
                    #pragma unroll
                    for(int j=0;j<4;++j){ hh[j]=(ushort)(u0[j]&0xffffu); ll[j]=(ushort)(u0[j]>>16); }
                    #pragma unroll
                    for(int j=0;j<4;++j){ hh[4+j]=(ushort)(u1[j]&0xffffu); ll[4+j]=(ushort)(u1[j]>>16); }
                    *(uint4*)(sb+boff)=*(uint4*)hh;
                    *(uint4*)(sb+SPLB+boff)=*(uint4*)ll;
                } else {
                    *(uint4*)(sb+boff)=r0[t];
                }
            }
        }
    };

    auto zero_rows=[&](){
        for(int z=tid; z<NB*SMP*PL*C8; z+=256){
            int nb=z/(SMP*PL*C8), rz=z-nb*(SMP*PL*C8);
            int s=rz/(PL*C8), rz2=rz-s*(PL*C8), pl=rz2/C8, g=rz2-pl*C8;
            *(uint4*)(sb + nb*BUFB + s*SAMB + pl*SPLB + IHW*RB + (g<<4)) = make_uint4(0,0,0,0);
        }
    };

    auto do_mfma=[&](int bufb, int c){
        const int ic0=c*ICC;
        __builtin_amdgcn_s_setprio(1);
        #pragma unroll
        for(int kk=0;kk<4;++kk){
            #pragma unroll
            for(int ks=0;ks<KS;++ks){
                short8v bhv[NT]; short8v blv[SPLIT?NT:1];
                #pragma unroll
                for(int n=0;n<NT;++n){
                    int col=n0+n*16+l15;
                    size_t widx=((size_t)kk*OC+col)*IC+ic0+ks*32+lq*8;
                    bhv[n]=*(const short8v*)(wt_hi+widx);
                    if constexpr(SPLIT) blv[n]=*(const short8v*)(wt_lo+widx);
                }
                #pragma unroll
                for(int s=0;s<SMP;++s){
                    const int sbase=bufb + s*SAMB;
                    #pragma unroll
                    for(int m=0;m<MT;++m){
                        int off=sbase + arow[kk][m]*RB + ((((ks<<2)|lq)^(arow[kk][m]&7))<<4);
                        short8v ah=*(const short8v*)(sb+off);
                        if constexpr(SPLIT){
                            short8v al=*(const short8v*)(sb+SPLB+off);
                            #pragma unroll
                            for(int n=0;n<NT;++n){
                                acc[s][m][n]=__builtin_amdgcn_mfma_f32_16x16x32_bf16(ah,bhv[n],acc[s][m][n],0,0,0);
                                acc[s][m][n]=__builtin_amdgcn_mfma_f32_16x16x32_bf16(ah,blv[n],acc[s][m][n],0,0,0);
                                acc[s][m][n]=__builtin_amdgcn_mfma_f32_16x16x32_bf16(al,bhv[n],acc[s][m][n],0,0,0);
                            }
                        } else {
                            #pragma unroll
                            for(int n=0;n<NT;++n)
                                acc[s][m][n]=__builtin_amdgcn_mfma_f32_16x16x32_bf16(ah,bhv[n],acc[s][m][n],0,0,0);
                        }
                    }
                }
            }
        }
        __builtin_amdgcn_s_setprio(0);
    };

    if constexpr(NB==1){
        stage_load(0);
        zero_rows();
        for(int c=0;c<NCH;++c){
            if(c) __syncthreads();
            stage_write(0);
            __syncthreads();
            if(c+1<NCH) stage_load(c+1);
            do_mfma(0,c);
        }
    } else {
        stage_load(0);
        stage_write(0);
        zero_rows();
        __syncthreads();
        for(int c=0;c<NCH;++c){
            if(c+1<NCH) stage_load(c+1);
            do_mfma((c&1)*BUFB,c);
            if(c+1<NCH){
                stage_write(((c+1)&1)*BUFB);
                __syncthreads();
            }
        }
    }

    const float rs=(float)(1.0/sqrt(1.0+1e-3));
    float lsum=0.f, colsum=0.f;
    #pragma unroll
    for(int s=0;s<SMP;++s){
        const int b=b0+s;
        #pragma unroll
        for(int n=0;n<NT;++n){
            int col=n0+n*16+l15;
            float bi=bias[col];
            float gsc=0.f, bt=0.f;
            if constexpr(HASBN){ gsc=gamma[col]*rs; bt=beta[col]; }
            #pragma unroll
            for(int m=0;m<MT;++m){
                #pragma unroll
                for(int j=0;j<4;++j){
                    int p=m*16+lq*4+j;
                    if(p<NPOS){
                        float vx=acc[s][m][n][j]+bi;
                        if constexpr(HASBN) vx=fmaxf(fmaf(vx,gsc,bt),0.f);
                        size_t g=(size_t)b*NPOS+p;
                        if constexpr(OUTFMT==0){
                            out_f[g*OC+col]=vx;
                        } else if constexpr(OUTFMT==1){
                            ushort h=bf16_hi(vx);
                            ushort lo=bf16_hi(vx-bf16_tof(h));
                            out_pk[g*OC+col]=(uint)h | ((uint)lo<<16);
                        } else {
                            out_bf[g*OC+col]=bf16_hi(vx);
                        }
                        if constexpr(FUSE){
                            int id=ids[b*L+p];
                            float mm=(masks[b*L+p]>=1)?1.f:0.f;
                            float h=table[(size_t)id*64+col]*mm;
                            float df=h-vx;
                            lsum=fmaf(df,df,lsum);
                            colsum+=vx;
                        }
                    }
                }
            }
        }
    }

    if constexpr(FUSE){
        const int b=b0;
        float mc=0.f;
        for(int l=lane;l<L;l+=64) mc += (masks[b*L+l]>=1)?1.f:0.f;
        #pragma unroll
        for(int off=32;off;off>>=1) mc+=__shfl_xor(mc,off);
        colsum += __shfl_xor(colsum,16);
        colsum += __shfl_xor(colsum,32);
        if(lq==0) out_mean[b*64 + n0 + l15] = colsum/mc;
        #pragma unroll
        for(int off=32;off;off>>=1) lsum+=__shfl_xor(lsum,off);
        __syncthreads();
        float* red=(float*)sb;
        if(lane==0) red[wv]=lsum;
        __syncthreads();
        if(tid==0) atomicAdd(acc_g+0, red[0]+red[1]+red[2]+red[3]);
    }
}

__device__ inline int xswz(int row, int sl){ return (sl ^ (row&31) ^ ((row>>3)&7)) << 4; }

// ---------------------------------------------------------------------------
// xsq: Sum x^2 only. Hi plane only (32 KB LDS), 512 threads, 1 sample/block,
// 8 waves x 64 cols (2 passes of 2 col-chunks; each A-read feeds 2 MFMAs).
// ---------------------------------------------------------------------------
__global__ __launch_bounds__(512)
void xsq_k(const uint* __restrict__ in_pk,
           const ushort* __restrict__ wx,                        // EW3H
           const float* __restrict__ xbias,                      // e_b3
           float* __restrict__ acc_g)
{
    constexpr int NPOS=49, OW=7, MT=4;
    constexpr int ROWB=512;

    __shared__ ushort s_a[64*256];          // hi plane only = 32 KB
    char* sb=(char*)s_a;

    const int v=blockIdx.x;
    const int b=(v&7)*(B/8)+(v>>3);
    const int tid=threadIdx.x, lane=tid&63, wv=tid>>6;
    const int l15=lane&15, lq=lane>>4;

    #pragma unroll
    for(int t=0;t<4;++t){
        int idx=tid+t*512;
        int row=idx>>5, sl=idx&31;
        const uint* src=in_pk+((size_t)b*64+row)*256+sl*8;
        uint4 u0=*(const uint4*)src, u1=*(const uint4*)(src+4);
        const uint* p0=(const uint*)&u0;
        const uint* p1=(const uint*)&u1;
        ushort hh[8];
        #pragma unroll
        for(int j=0;j<4;++j){ hh[j]=(ushort)(p0[j]&0xffffu); hh[4+j]=(ushort)(p1[j]&0xffffu); }
        *(uint4*)(sb+row*ROWB+xswz(row,sl))=*(uint4*)hh;
    }
    __syncthreads();

    int arow[4][MT];
    #pragma unroll
    for(int kk=0;kk<4;++kk){
        const int ky=kk>>1, kx=kk&1;
        #pragma unroll
        for(int m=0;m<MT;++m){
            int p=m*16+l15;
            int py=p/OW, px=p-py*OW;
            arow[kk][m]= (p<NPOS) ? (py+ky)*8+(px+kx) : 0;
        }
    }

    float xs=0.f;
    #pragma unroll
    for(int cc=0;cc<2;++cc){
        f32x4 accx[MT][2];
        #pragma unroll
        for(int m=0;m<MT;++m){ accx[m][0]=(f32x4)0.0f; accx[m][1]=(f32x4)0.0f; }
        const int col0=wv*64+cc*32+l15;
        __builtin_amdgcn_s_setprio(1);
        #pragma unroll
        for(int kk=0;kk<4;++kk){
            #pragma unroll
            for(int ks=0;ks<8;++ks){
                short8v bx0=*(const short8v*)(wx+((size_t)kk*512+col0)*256+ks*32+lq*8);
                short8v bx1=*(const short8v*)(wx+((size_t)kk*512+col0+16)*256+ks*32+lq*8);
                const int slb=ks*4+lq;
                #pragma unroll
                for(int m=0;m<MT;++m){
                    int r=arow[kk][m];
                    short8v ah=*(const short8v*)(sb+r*ROWB+xswz(r,slb));
                    accx[m][0]=__builtin_amdgcn_mfma_f32_16x16x32_bf16(ah,bx0,accx[m][0],0,0,0);
                    accx[m][1]=__builtin_amdgcn_mfma_f32_16x16x32_bf16(ah,bx1,accx[m][1],0,0,0);
                }
            }
        }
        __builtin_amdgcn_s_setprio(0);
        #pragma unroll
        for(int n=0;n<2;++n){
            const float bi=xbias[col0+n*16];
            #pragma unroll
            for(int m=0;m<MT;++m){
                #pragma unroll
                for(int j=0;j<4;++j){
                    int p=m*16+lq*4+j;
                    if(p<NPOS){ float vv=accx[m][n][j]+bi; xs=fmaf(vv,vv,xs); }
                }
            }
        }
    }
    #pragma unroll
    for(int off=32;off;off>>=1) xs+=__shfl_xor(xs,off);

    __syncthreads();
    float* f=(float*)sb;
    if(lane==0) f[wv]=xs;
    __syncthreads();
    if(tid==0) atomicAdd(acc_g+1, f[0]+f[1]+f[2]+f[3]+f[4]+f[5]+f[6]+f[7]);
}

// ---------------------------------------------------------------------------
// dot: folded-codebook dots + argmin. Hi+lo (64 KB LDS), 512 threads, K-split.
// ---------------------------------------------------------------------------
__global__ __launch_bounds__(512)
void dot_k(const uint* __restrict__ in_pk,
           const ushort* __restrict__ w3bh, const ushort* __restrict__ w3bl,
           const float* __restrict__ cbn, const float* __restrict__ dotb,
           int* __restrict__ qidx, float* __restrict__ acc_g,
           int* __restrict__ cnt, int* __restrict__ wl)
{
    constexpr int NPOS=49, OW=7, MT=4;
    constexpr int ROWB=512;
    constexpr int PLB=64*ROWB;

    __shared__ ushort s_a[2*64*256];        // hi + lo = 64 KB
    char* sb=(char*)s_a;

    const int v=blockIdx.x;
    const int b=(v&7)*(B/8)+(v>>3);
    const int tid=threadIdx.x, lane=tid&63, wv=tid>>6;
    const int l15=lane&15, lq=lane>>4;

    #pragma unroll
    for(int t=0;t<4;++t){
        int idx=tid+t*512;
        int row=idx>>5, sl=idx&31;
        const uint* src=in_pk+((size_t)b*64+row)*256+sl*8;
        uint4 u0=*(const uint4*)src, u1=*(const uint4*)(src+4);
        const uint* p0=(const uint*)&u0;
        const uint* p1=(const uint*)&u1;
        ushort hh[8], ll[8];
        #pragma unroll
        for(int j=0;j<4;++j){ hh[j]=(ushort)(p0[j]&0xffffu); ll[j]=(ushort)(p0[j]>>16); }
        #pragma unroll
        for(int j=0;j<4;++j){ hh[4+j]=(ushort)(p1[j]&0xffffu); ll[4+j]=(ushort)(p1[j]>>16); }
        int boff=row*ROWB+xswz(row,sl);
        *(uint4*)(sb+boff)=*(uint4*)hh;
        *(uint4*)(sb+PLB+boff)=*(uint4*)ll;
    }
    __syncthreads();

    int arow[4][MT];
    #pragma unroll
    for(int kk=0;kk<4;++kk){
        const int ky=kk>>1, kx=kk&1;
        #pragma unroll
        for(int m=0;m<MT;++m){
            int p=m*16+l15;
            int py=p/OW, px=p-py*OW;
            arow[kk][m]= (p<NPOS) ? (py+ky)*8+(px+kx) : 0;
        }
    }

    const int cold=(wv&3)*16+l15;
    const int ks0=(wv>>2)*4;
    f32x4 accd[MT];
    #pragma unroll
    for(int m=0;m<MT;++m) accd[m]=(f32x4)0.0f;

    __builtin_amdgcn_s_setprio(1);
    #pragma unroll
    for(int kk=0;kk<4;++kk){
        #pragma unroll
        for(int kq2=0;kq2<4;++kq2){
            const int ks=ks0+kq2;
            size_t wdx=((size_t)kk*64+cold)*256+ks*32+lq*8;
            short8v bdh=*(const short8v*)(w3bh+wdx);
            short8v bdl=*(const short8v*)(w3bl+wdx);
            const int slb=ks*4+lq;
            #pragma unroll
            for(int m=0;m<MT;++m){
                int r=arow[kk][m];
                int off=r*ROWB+xswz(r,slb);
                short8v ah=*(const short8v*)(sb+off);
                short8v al=*(const short8v*)(sb+PLB+off);
                accd[m]=__builtin_amdgcn_mfma_f32_16x16x32_bf16(ah,bdh,accd[m],0,0,0);
                accd[m]=__builtin_amdgcn_mfma_f32_16x16x32_bf16(ah,bdl,accd[m],0,0,0);
                accd[m]=__builtin_amdgcn_mfma_f32_16x16x32_bf16(al,bdh,accd[m],0,0,0);
            }
        }
    }
    __builtin_amdgcn_s_setprio(0);

    __syncthreads();
    float* f=(float*)sb;
    if(wv>=4){
        float* dst=f+((wv-4)*64+lane)*16;
        #pragma unroll
        for(int m=0;m<MT;++m){
            #pragma unroll
            for(int j=0;j<4;++j) dst[m*4+j]=accd[m][j];
        }
    }
    __syncthreads();

    float* sd1=f+4096;
    int*   sk =(int*)(f+4096+256);
    float* sd2=f+4096+512;
    if(wv<4){
        const float* srcp=f+(wv*64+lane)*16;
        float cb=cbn[cold], db=dotb[cold];
        #pragma unroll
        for(int m=0;m<MT;++m){
            #pragma unroll
            for(int j=0;j<4;++j){
                int p=m*16+lq*4+j;
                float dtot=accd[m][j]+srcp[m*4+j];
                float d1=cb-2.f*(dtot+db);
                int   k1=cold;
                float d2=3.4e38f;
                #pragma unroll
                for(int off=1;off<16;off<<=1){
                    float od1=__shfl_xor(d1,off);
                    int   ok1=__shfl_xor(k1,off);
                    float od2=__shfl_xor(d2,off);
                    if(od1<d1 || (od1==d1 && ok1<k1)){ d2=fminf(d1,od2); d1=od1; k1=ok1; }
                    else                              { d2=fminf(d2,od1); }
                }
                if(l15==0 && p<NPOS){ sd1[p*4+wv]=d1; sk[p*4+wv]=k1; sd2[p*4+wv]=d2; }
            }
        }
    }
    __syncthreads();

    {
        float lsum=0.f;
        if(tid<NPOS){
            float d1=sd1[tid*4+0]; int k1=sk[tid*4+0]; float d2=sd2[tid*4+0];
            #pragma unroll
            for(int w=1;w<4;++w){
                float D1=sd1[tid*4+w]; int K1=sk[tid*4+w]; float D2=sd2[tid*4+w];
                if(D1<d1){ d2=fminf(d1,D2); d1=D1; k1=K1; }
                else     { d2=fminf(d2,D1); }
            }
            qidx[b*49+tid]=k1;
            if(d2-d1<=MARGIN){ int t=atomicAdd(cnt,1); wl[t]=b*49+tid; }
            lsum=d1;
        }
        if(tid<64){
            #pragma unroll
            for(int off=32;off;off>>=1) lsum+=__shfl_xor(lsum,off);
            if(tid==0) atomicAdd(acc_g+1, lsum);
        }
    }
}

// ---------------------------------------------------------------------------
// deconv1 as gather-sum over BW1.
// ---------------------------------------------------------------------------
__global__ __launch_bounds__(256)
void dgather_k(const int* __restrict__ qidx, const float* __restrict__ bw1,
               const float* __restrict__ b1, const float* __restrict__ g1s,
               const float* __restrict__ be1, ushort* __restrict__ G1)
{
    const int b=blockIdx.x, tid=threadIdx.x;
    const int pg=tid>>2, og=(tid&3)*64;
    const int py=pg>>3, px=pg&7;

    float a[64];
    #pragma unroll
    for(int j=0;j<64;++j) a[j]=0.f;

    #pragma unroll
    for(int tap=0;tap<4;++tap){
        int iy=py+(tap>>1)-1, ix=px+(tap&1)-1;
        if((unsigned)iy<7u && (unsigned)ix<7u){
            int kq=qidx[b*49+iy*7+ix];
            const float4* src=(const float4*)(bw1+((size_t)(tap*64+kq))*256+og);
            #pragma unroll
            for(int j=0;j<16;++j){
                float4 vv=src[j];
                a[4*j+0]+=vv.x; a[4*j+1]+=vv.y; a[4*j+2]+=vv.z; a[4*j+3]+=vv.w;
            }
        }
    }
    const float rs=(float)(1.0/sqrt(1.0+1e-3));
    #pragma unroll
    for(int j=0;j<64;++j){
        int col=og+j;
        float vv=a[j]+b1[col];
        vv=fmaxf(fmaf(vv, g1s[col]*rs, be1[col]), 0.f);
        G1[((size_t)b*64+pg)*256+col]=bf16_hi(vv);
    }
}

// ---------------------------------------------------------------------------
// f64 re-verification of flagged rows (full receptive field from scratch).
// Round-16 byte-identical body; grid 8192.
// ---------------------------------------------------------------------------
__global__ __launch_bounds__(256)
void recompute_k(const int* __restrict__ wl, const int* __restrict__ cnt,
                 const int* __restrict__ ids, const int* __restrict__ masks,
                 const float* __restrict__ table, const float* __restrict__ book,
                 const float* __restrict__ e_w1, const float* __restrict__ e_b1,
                 const float* __restrict__ e_g1, const float* __restrict__ e_be1,
                 const float* __restrict__ e_w2, const float* __restrict__ e_b2,
                 const float* __restrict__ e_g2, const float* __restrict__ e_be2,
                 const float* __restrict__ e_w3, const float* __restrict__ e_b3,
                 int* __restrict__ qidx)
{
    __shared__ double s_h[16*64];
    __shared__ double s_a1[9*128];
    __shared__ double s_a2[4*256];
    __shared__ double s_x[512];
    __shared__ double s_d[256];

    const int tid = threadIdx.x;
    const double rs = 1.0 / sqrt(1.0 + 1e-3);
    const int n = *cnt;

    for (int wi = blockIdx.x; wi < n; wi += gridDim.x) {
        const int row = wl[wi];
        const int b = row / 49, p = row % 49;
        const int py = p / 7, px = p % 7;

        for (int i = tid; i < 16*64; i += 256) {
            int cell = i >> 6, d = i & 63;
            int l = (py + (cell >> 2)) * 10 + (px + (cell & 3));
            int id = ids[b*100 + l];
            double m = (masks[b*100 + l] >= 1) ? 1.0 : 0.0;
            s_h[i] = (double)table[(size_t)id*64 + d] * m;
        }
        __syncthreads();

        for (int i = tid; i < 9*128; i += 256) {
            int cell = i >> 7, oc = i & 127;
            int ry = cell / 3, rx = cell % 3;
            double s = 0.0;
            #pragma unroll
            for (int kk = 0; kk < 4; ++kk) {
                int icell = (ry + (kk>>1))*4 + (rx + (kk&1));
                const double* hh = s_h + icell*64;
                const float* ww = e_w1 + (kk*64)*128 + oc;
                for (int ic = 0; ic < 64; ++ic)
                    s = fma(hh[ic], (double)ww[ic*128], s);
            }
            s += (double)e_b1[oc];
            s = s * ((double)e_g1[oc] * rs) + (double)e_be1[oc];
            s_a1[i] = s > 0.0 ? s : 0.0;
        }
        __syncthreads();

        for (int i = tid; i < 4*256; i += 256) {
            int cell = i >> 8, oc = i & 255;
            int qy = cell >> 1, qx = cell & 1;
            double s = 0.0;
            #pragma unroll
            for (int kk = 0; kk < 4; ++kk) {
                int icell = (qy + (kk>>1))*3 + (qx + (kk&1));
                const double* aa = s_a1 + icell*128;
                const float* ww = e_w2 + (kk*128)*256 + oc;
                for (int ic = 0; ic < 128; ++ic)
                    s = fma(aa[ic], (double)ww[ic*256], s);
            }
            s += (double)e_b2[oc];
            s = s * ((double)e_g2[oc] * rs) + (double)e_be2[oc];
            s_a2[i] = s > 0.0 ? s : 0.0;
        }
        __syncthreads();

        for (int i = tid; i < 512; i += 256) {
            double s = 0.0;
            #pragma unroll
            for (int kk = 0; kk < 4; ++kk) {
                const double* aa = s_a2 + kk*256;
                const float* ww = e_w3 + (kk*256)*512 + i;
                for (int ic = 0; ic < 256; ++ic)
                    s = fma(aa[ic], (double)ww[ic*512], s);
            }
            s_x[i] = s + (double)e_b3[i];
        }
        __syncthreads();

        {
            int k = tid & 63, seg = tid >> 6;
            const float* cr = book + k*512 + seg*128;
            const double* xr = s_x + seg*128;
            double s = 0.0;
            for (int c = 0; c < 128; ++c) {
                double dd = xr[c] - (double)cr[c];
                s = fma(dd, dd, s);
            }
            s_d[seg*64 + k] = s;
        }
        __syncthreads();

        if (tid < 64) {
            double dv = s_d[tid] + s_d[64+tid] + s_d[128+tid] + s_d[192+tid];
            int kk2 = tid;
            #pragma unroll
            for (int off = 32; off > 0; off >>= 1) {
                double od = __shfl_xor(dv, off);
                int    ok = __shfl_xor(kk2, off);
                if (od < dv || (od == dv && ok < kk2)) { dv = od; kk2 = ok; }
            }
            if (tid == 0) qidx[row] = kk2;
        }
        __syncthreads();
    }
}

__global__ void loss_k(const float* __restrict__ acc, float* __restrict__ out_loss)
{
    float l1 = acc[0] / 13107200.f;
    float l2 = acc[1] / 51380224.f;
    out_loss[0] = l1 + l2 + 0.25f * l2;
}

// ---------------------------------------------------------------------------
extern "C" void kernel_launch(void* const* d_in, const int* in_sizes, int n_in,
                              void* d_out, int out_size, void* d_ws, size_t ws_size,
                              hipStream_t stream)
{
    const int*   ids   = (const int*)d_in[0];
    const int*   masks = (const int*)d_in[1];
    const float* table = (const float*)d_in[2];
    const float* book  = (const float*)d_in[3];
    const float* e_w1  = (const float*)d_in[4];
    const float* e_b1  = (const float*)d_in[5];
    const float* e_g1  = (const float*)d_in[6];
    const float* e_be1 = (const float*)d_in[7];
    const float* e_w2  = (const float*)d_in[8];
    const float* e_b2  = (const float*)d_in[9];
    const float* e_g2  = (const float*)d_in[10];
    const float* e_be2 = (const float*)d_in[11];
    const float* e_w3  = (const float*)d_in[12];
    const float* e_b3  = (const float*)d_in[13];
    const float* d_w1  = (const float*)d_in[14];
    const float* d_b1  = (const float*)d_in[15];
    const float* d_g1  = (const float*)d_in[16];
    const float* d_be1 = (const float*)d_in[17];
    const float* d_w2  = (const float*)d_in[18];
    const float* d_b2  = (const float*)d_in[19];
    const float* d_g2  = (const float*)d_in[20];
    const float* d_be2 = (const float*)d_in[21];
    const float* d_w3  = (const float*)d_in[22];
    const float* d_b3  = (const float*)d_in[23];

    float*  ws  = (float*)d_ws;
    uint*   A1P = (uint*)(ws + R0_OFF);   // [B*81*128] u32 hi|lo
    uint*   A2P = (uint*)(ws + R1_OFF);   // [B*64*256] u32 hi|lo
    ushort* G1  = (ushort*)(ws + R1_OFF); // [B*64*256] bf16 (after dot/xsq)
    ushort* G2  = (ushort*)(ws + R0_OFF); // [B*81*128] bf16 (after conv2)
    int*    IDX = (int*)(ws + IDX_OFF);
    float*  CBN = ws + CBN_OFF;
    int*    CNT = (int*)(ws + CNT_OFF);
    float*  ACC = ws + ACC_OFF;
    int*    WL  = (int*)(ws + WL_OFF);
    ushort* WB  = (ushort*)(ws + WB_OFF);
    float*  BW1 = ws + BW1_OFF;
    float*  DOTB= ws + DOTB_OFF;

    float* out_mean = (float*)d_out;
    float* out_vqx  = (float*)d_out + (size_t)B * 64;
    float* out_loss = (float*)d_out + (size_t)B * 64 + (size_t)B * L * 64;

    prep_k<<<1, 256, 0, stream>>>(book, e_b3, CBN, DOTB, ACC, CNT);
    wprep_k<<<512, 256, 0, stream>>>(e_w1, e_w2, e_w3, d_w2, d_w3, WB);
    w3b_k<<<256, 256, 0, stream>>>(e_w3, book, WB);
    bw1_k<<<256, 256, 0, stream>>>(d_w1, book, BW1);

    // encoder (split-bf16) — round-10 configs
    sconv_k<10,10, 64,128,0,1,true ,true ,1, 64,6,1,false,1,true ><<<B,   256,0,stream>>>(
        nullptr, nullptr, ids, masks, table,
        WB+EW1H, WB+EW1L, e_b1, e_g1, e_be1, nullptr, A1P, nullptr, nullptr, nullptr);
    sconv_k< 9, 9,128,256,0,3,true ,true ,2, 64,4,1,false,1,true ><<<B*2, 256,0,stream>>>(
        A1P, nullptr, nullptr, nullptr, nullptr,
        WB+EW2H, WB+EW2L, e_b2, e_g2, e_be2, nullptr, A2P, nullptr, nullptr, nullptr);

    // Sum x^2 (lean, hi-only) + folded-codebook dots/argmin (K-split)
    xsq_k<<<B, 512, 0, stream>>>(A2P, WB+EW3H, e_b3, ACC);
    dot_k<<<B, 512, 0, stream>>>(A2P, WB+W3BH, WB+W3BL, CBN, DOTB, IDX, ACC, CNT, WL);

    // f64 re-verify flagged rows (round-16 kernel, grid 8192)
    recompute_k<<<8192, 256, 0, stream>>>(WL, CNT, ids, masks, table, book,
                                          e_w1, e_b1, e_g1, e_be1,
                                          e_w2, e_b2, e_g2, e_be2,
                                          e_w3, e_b3, IDX);

    // decoder: deconv1 = gather-sum; deconv2/3 = bf16 MFMA convs (round-10)
    dgather_k<<<B, 256, 0, stream>>>(IDX, BW1, d_b1, d_g1, d_be1, G1);
    sconv_k< 8, 8,256,128,1,4,true ,false,1, 64,6,2,false,1,true ><<<B,   256,0,stream>>>(
        nullptr, G1, nullptr, nullptr, nullptr,
        WB+DW2H, nullptr, d_b2, d_g2, d_be2, nullptr, nullptr, G2, nullptr, nullptr);
    sconv_k< 9, 9,128, 64,1,4,false,false,1, 64,7,0,true ,1,true ><<<B,   256,0,stream>>>(
        nullptr, G2, ids, masks, table,
        WB+DW3H, nullptr, d_b3, nullptr, nullptr, out_vqx, nullptr, nullptr, out_mean, ACC);

    loss_k<<<1, 1, 0, stream>>>(ACC, out_loss);
}

// Round 22
// 1082.512 us; speedup vs baseline: 1.0131x; 1.0071x over previous
//
#include <hip/hip_runtime.h>
#include <hip/hip_bf16.h>
#include <cstdint>
#include <cstddef>

// ---------------------------------------------------------------------------
// VQ-VAE forward (B=2048, L=100, D=64, K=64, CB=512) — v16.
// = v15 (round-21, 1090 us) with ONE change: xsq_k __launch_bounds__(512,2)
// to force VGPR+AGPR <= 128 (theory: unified-file accumulator regs push the
// true total to ~136, capping residency at 2 waves/SIMD — explains why all
// three structural xsq levers were null).
// Encoder: split-bf16 (hi+lo, 3 MFMAs) ~f32; decoder: plain bf16.
// Argmin exactness: margin 0.1 flag -> f64 full recompute of flagged rows.
// ---------------------------------------------------------------------------

typedef __attribute__((ext_vector_type(8))) short short8v;   // 8 bf16
typedef __attribute__((ext_vector_type(4))) float f32x4;

constexpr int B  = 2048;
constexpr int L  = 100;
constexpr int K  = 64;
constexpr int CB = 512;
#define MARGIN 0.1f

// ---- workspace layout (float-sized units) ----
constexpr size_t R0_OFF  = 0;          // A1P u32 -> G2 bf16
constexpr size_t R1_OFF  = 51380224;   // A2P u32 -> G1 bf16
constexpr size_t IDX_OFF = 84934656;   // 2048*49 ints
constexpr size_t CBN_OFF = 85035008;   // 64 norms
constexpr size_t CNT_OFF = 85035072;
constexpr size_t ACC_OFF = 85035088;
constexpr size_t WL_OFF  = 85035104;   // 100352 ints
constexpr size_t WB_OFF  = 85135456;   // bf16 weights (ushort units below)

// bf16 weight sub-offsets (ushort units), layout [4][OC][IC]
constexpr size_t EW1H=0,       EW1L=32768;
constexpr size_t EW2H=65536,   EW2L=196608;
constexpr size_t EW3H=327680;                   // [4][512][256] hi only
constexpr size_t DW2H=851968,  DW3H=983040;
constexpr size_t W3BH=1015808, W3BL=1081344;    // [4][64][256] hi/lo

constexpr size_t BW1_OFF  = WB_OFF + 573440;    // [4][64][256] f32
constexpr size_t DOTB_OFF = BW1_OFF + 65536;    // 64 f32

__device__ inline ushort bf16_hi(float f){ __hip_bfloat16 h=__float2bfloat16(f); return *(ushort*)&h; }
__device__ inline float  bf16_tof(ushort u){ __hip_bfloat16 h; *(ushort*)&h=u; return __bfloat162float(h); }

// ---------------------------------------------------------------------------
// weight prep: w[2,2,IC,OC] f32 -> Wt[kk][oc][ic] bf16 hi (+lo)
// ---------------------------------------------------------------------------
__device__ void wtrans(const float* __restrict__ w, int IC, int OC,
                       ushort* __restrict__ hi, ushort* __restrict__ lo,
                       int gid, int gsz)
{
    int tot = 4*IC*OC;
    for (int i = gid; i < tot; i += gsz) {
        int kk = i/(IC*OC), r = i - kk*(IC*OC), ic = r/OC, oc = r - ic*OC;
        float v = w[i];
        ushort h = bf16_hi(v);
        size_t dst = ((size_t)kk*OC + oc)*IC + ic;
        hi[dst] = h;
        if (lo) lo[dst] = bf16_hi(v - bf16_tof(h));
    }
}

__global__ __launch_bounds__(256)
void wprep_k(const float* e1, const float* e2, const float* e3,
             const float* d2, const float* d3, ushort* wb)
{
    int gid = blockIdx.x*256 + threadIdx.x, gsz = gridDim.x*256;
    wtrans(e1,  64, 128, wb+EW1H, wb+EW1L, gid, gsz);
    wtrans(e2, 128, 256, wb+EW2H, wb+EW2L, gid, gsz);
    wtrans(e3, 256, 512, wb+EW3H, nullptr, gid, gsz);
    wtrans(d2, 256, 128, wb+DW2H, nullptr, gid, gsz);
    wtrans(d3, 128,  64, wb+DW3H, nullptr, gid, gsz);
}

// ---------------------------------------------------------------------------
// W3B[kk][k][ic] = sum_cb e_w3[kk,ic,cb] * book[k,cb]  (hi/lo bf16)
// ---------------------------------------------------------------------------
__global__ __launch_bounds__(256)
void w3b_k(const float* __restrict__ e_w3, const float* __restrict__ book,
           ushort* __restrict__ wb)
{
    const int kk = blockIdx.x >> 6, k = blockIdx.x & 63, ic = threadIdx.x;
    const float4* wr = (const float4*)(e_w3 + ((size_t)(kk*256)+ic)*512);
    const float4* br = (const float4*)(book + (size_t)k*512);
    float s = 0.f;
    for (int c = 0; c < 128; ++c) {
        float4 a = wr[c], bb = br[c];
        s = fmaf(a.x,bb.x,fmaf(a.y,bb.y,fmaf(a.z,bb.z,fmaf(a.w,bb.w,s))));
    }
    size_t dst = ((size_t)(kk*64+k))*256 + ic;
    ushort h = bf16_hi(s);
    wb[W3BH+dst] = h;
    wb[W3BL+dst] = bf16_hi(s - bf16_tof(h));
}

// ---------------------------------------------------------------------------
// BW1[tap][k][oc] = sum_ic book[k,ic] * d_w1[tap,ic,oc]   (f32)
// ---------------------------------------------------------------------------
__global__ __launch_bounds__(256)
void bw1_k(const float* __restrict__ d_w1, const float* __restrict__ book,
           float* __restrict__ bw1)
{
    const int tap = blockIdx.x >> 6, k = blockIdx.x & 63, oc = threadIdx.x;
    const float* br = book + (size_t)k*512;
    const float* wr = d_w1 + (size_t)(tap*512)*256 + oc;
    float s = 0.f;
    for (int ic = 0; ic < 512; ++ic)
        s = fmaf(br[ic], wr[(size_t)ic*256], s);
    bw1[((size_t)(tap*64+k))*256 + oc] = s;
}

// ---------------------------------------------------------------------------
// prep: code norms, dotbias, zero accumulators + worklist count
// ---------------------------------------------------------------------------
__global__ __launch_bounds__(256)
void prep_k(const float* __restrict__ book, const float* __restrict__ e_b3,
            float* __restrict__ cbn, float* __restrict__ dotb,
            float* __restrict__ acc, int* __restrict__ cnt)
{
    const int t = threadIdx.x;
    if (t < 64) {
        const float* r = book + t * 512;
        float s = 0.f, d = 0.f;
        for (int c = 0; c < 512; ++c) { s = fmaf(r[c], r[c], s); d = fmaf(e_b3[c], r[c], d); }
        cbn[t] = s; dotb[t] = d;
    }
    if (t == 64 || t == 65) acc[t-64] = 0.f;
    if (t == 66) *cnt = 0;
}

// ---------------------------------------------------------------------------
// Per-sample MFMA conv (round-9/10 proven). Block = (SMP samples, oc-slice),
// XCD-remapped. DBUF: double-buffered LDS, 1 barrier/chunk, T14 prefetch,
// setprio around MFMA cluster.
// MODE 1: table gather+mask; 3: packed u32 hi|lo; 4: bf16.
// OUTFMT 0: f32; 1: packed u32; 2: bf16.  FUSE (SMP=1): vq_mean + loss1.
// ---------------------------------------------------------------------------
template<int IH,int IW,int IC,int OC,int PAD,int MODE,bool HASBN,bool SPLIT,
         int OCS,int ICC,int MT,int OUTFMT,bool FUSE,int SMP,bool DBUF>
__global__ __launch_bounds__(256)
void sconv_k(const uint* __restrict__ in_pk, const ushort* __restrict__ in_bf,
             const int* __restrict__ ids, const int* __restrict__ masks,
             const float* __restrict__ table,
             const ushort* __restrict__ wt_hi, const ushort* __restrict__ wt_lo,
             const float* __restrict__ bias, const float* __restrict__ gamma,
             const float* __restrict__ beta,
             float* __restrict__ out_f, uint* __restrict__ out_pk,
             ushort* __restrict__ out_bf, float* __restrict__ out_mean,
             float* __restrict__ acc_g)
{
    constexpr int OH=IH+2*PAD-1, OW=IW+2*PAD-1, NPOS=OH*OW, IHW=IH*IW;
    constexpr int OCB=OC/OCS, NPW=OCB/4, NT=NPW/16;
    constexpr int NCH=IC/ICC, KS=ICC/32;
    constexpr int PL=SPLIT?2:1;
    constexpr int NB=(DBUF && NCH>1)?2:1;
    constexpr int AROWS=IHW+1, RB=ICC*2;
    constexpr int C8=ICC/8;
    constexpr int NITEMS=SMP*IHW*C8;
    constexpr int SI=(NITEMS+255)/256;
    constexpr bool EXACT=(SI*256==NITEMS);
    constexpr int SPLB=AROWS*RB;
    constexpr int SAMB=PL*SPLB;
    constexpr int BUFB=SMP*SAMB;

    __shared__ ushort s_a[NB*SMP*PL*AROWS*ICC];
    char* sb=(char*)s_a;

    const int v=blockIdx.x, r8=v&7, iv=v>>3;
    const int b0 = (r8*(B/SMP/8) + iv/OCS)*SMP;
    const int sl = iv - (iv/OCS)*OCS;

    const int tid=threadIdx.x, lane=tid&63, wv=tid>>6;
    const int l15=lane&15, lq=lane>>4;
    const int n0=sl*OCB + wv*NPW;

    int arow[4][MT];
    #pragma unroll
    for(int kk=0;kk<4;++kk){
        const int ky=kk>>1, kx=kk&1;
        #pragma unroll
        for(int m=0;m<MT;++m){
            int p=m*16+l15;
            int py=p/OW, px=p-py*OW;
            int ty=py+ky-PAD, tx=px+kx-PAD;
            bool ok=(p<NPOS)&&((unsigned)ty<(unsigned)IH)&&((unsigned)tx<(unsigned)IW);
            arow[kk][m]= ok ? ty*IW+tx : IHW;
        }
    }

    f32x4 acc[SMP][MT][NT];
    #pragma unroll
    for(int s=0;s<SMP;++s)
        #pragma unroll
        for(int m=0;m<MT;++m)
            #pragma unroll
            for(int n=0;n<NT;++n) acc[s][m][n]=(f32x4)0.0f;

    uint4 r0[SI];
    uint4 r1[(MODE==1||MODE==3)?SI:1];
    float msk[(MODE==1)?SI:1];

    auto stage_load=[&](int c){
        const int ic0=c*ICC;
        #pragma unroll
        for(int t=0;t<SI;++t){
            int idx=tid+t*256;
            if(EXACT || idx<NITEMS){
                int row=idx/C8, g=idx-row*C8;
                int s=row/IHW, r=row-s*IHW;
                if constexpr(MODE==1){
                    int id=ids[(b0+s)*L+r];
                    msk[t]=(masks[(b0+s)*L+r]>=1)?1.f:0.f;
                    const float* src=table+(size_t)id*64+g*8;
                    r0[t]=*(const uint4*)src;
                    r1[t]=*(const uint4*)(src+4);
                } else if constexpr(MODE==3){
                    const uint* src=in_pk+((size_t)(b0+s)*IHW+r)*IC+ic0+g*8;
                    r0[t]=*(const uint4*)src;
                    r1[t]=*(const uint4*)(src+4);
                } else {
                    r0[t]=*(const uint4*)(in_bf+((size_t)(b0+s)*IHW+r)*IC+ic0+g*8);
                }
            }
        }
    };

    auto stage_write=[&](int bufb){
        #pragma unroll
        for(int t=0;t<SI;++t){
            int idx=tid+t*256;
            if(EXACT || idx<NITEMS){
                int row=idx/C8, g=idx-row*C8;
                int s=row/IHW, r=row-s*IHW;
                int boff=bufb + s*SAMB + r*RB + ((g^(r&7))<<4);
                if constexpr(MODE==1){
                    const float* f0=(const float*)&r0[t];
                    const float* f1=(const float*)&r1[t];
                    float vv[8]={f0[0]*msk[t],f0[1]*msk[t],f0[2]*msk[t],f0[3]*msk[t],
                                 f1[0]*msk[t],f1[1]*msk[t],f1[2]*msk[t],f1[3]*msk[t]};
                    ushort hh[8], ll[8];
                    #pragma unroll
                    for(int j=0;j<8;++j){ hh[j]=bf16_hi(vv[j]); ll[j]=bf16_hi(vv[j]-bf16_tof(hh[j])); }
                    *(uint4*)(sb+boff)=*(uint4*)hh;
                    *(uint4*)(sb+SPLB+boff)=*(uint4*)ll;
                } else if constexpr(MODE==3){
                    const uint* u0=(const uint*)&r0[t];
                    const uint* u1=(const uint*)&r1[t];
                    ushort hh[8], ll[8];
                    #pragma unroll
                    for(int j=0;j<4;++j){ hh[j]=(ushort)(u0[j]&0xffffu); ll[j]=(ushort)(u0[j]>>16); }
                    #pragma unroll
                    for(int j=0;j<4;++j){ hh[4+j]=(ushort)(u1[j]&0xffffu); ll[4+j]=(ushort)(u1[j]>>16); }
                    *(uint4*)(sb+boff)=*(uint4*)hh;
                    *(uint4*)(sb+SPLB+boff)=*(uint4*)ll;
                } else {
                    *(uint4*)(sb+boff)=r0[t];
                }
            }
        }
    };

    auto zero_rows=[&](){
        for(int z=tid; z<NB*SMP*PL*C8; z+=256){
            int nb=z/(SMP*PL*C8), rz=z-nb*(SMP*PL*C8);
            int s=rz/(PL*C8), rz2=rz-s*(PL*C8), pl=rz2/C8, g=rz2-pl*C8;
            *(uint4*)(sb + nb*BUFB + s*SAMB + pl*SPLB + IHW*RB + (g<<4)) = make_uint4(0,0,0,0);
        }
    };

    auto do_mfma=[&](int bufb, int c){
        const int ic0=c*ICC;
        __builtin_amdgcn_s_setprio(1);
        #pragma unroll
        for(int kk=0;kk<4;++kk){
            #pragma unroll
            for(int ks=0;ks<KS;++ks){
                short8v bhv[NT]; short8v blv[SPLIT?NT:1];
                #pragma unroll
                for(int n=0;n<NT;++n){
                    int col=n0+n*16+l15;
                    size_t widx=((size_t)kk*OC+col)*IC+ic0+ks*32+lq*8;
                    bhv[n]=*(const short8v*)(wt_hi+widx);
                    if constexpr(SPLIT) blv[n]=*(const short8v*)(wt_lo+widx);
                }
                #pragma unroll
                for(int s=0;s<SMP;++s){
                    const int sbase=bufb + s*SAMB;
                    #pragma unroll
                    for(int m=0;m<MT;++m){
                        int off=sbase + arow[kk][m]*RB + ((((ks<<2)|lq)^(arow[kk][m]&7))<<4);
                        short8v ah=*(const short8v*)(sb+off);
                        if constexpr(SPLIT){
                            short8v al=*(const short8v*)(sb+SPLB+off);
                            #pragma unroll
                            for(int n=0;n<NT;++n){
                                acc[s][m][n]=__builtin_amdgcn_mfma_f32_16x16x32_bf16(ah,bhv[n],acc[s][m][n],0,0,0);
                                acc[s][m][n]=__builtin_amdgcn_mfma_f32_16x16x32_bf16(ah,blv[n],acc[s][m][n],0,0,0);
                                acc[s][m][n]=__builtin_amdgcn_mfma_f32_16x16x32_bf16(al,bhv[n],acc[s][m][n],0,0,0);
                            }
                        } else {
                            #pragma unroll
                            for(int n=0;n<NT;++n)
                                acc[s][m][n]=__builtin_amdgcn_mfma_f32_16x16x32_bf16(ah,bhv[n],acc[s][m][n],0,0,0);
                        }
                    }
                }
            }
        }
        __builtin_amdgcn_s_setprio(0);
    };

    if constexpr(NB==1){
        stage_load(0);
        zero_rows();
        for(int c=0;c<NCH;++c){
            if(c) __syncthreads();
            stage_write(0);
            __syncthreads();
            if(c+1<NCH) stage_load(c+1);
            do_mfma(0,c);
        }
    } else {
        stage_load(0);
        stage_write(0);
        zero_rows();
        __syncthreads();
        for(int c=0;c<NCH;++c){
            if(c+1<NCH) stage_load(c+1);
            do_mfma((c&1)*BUFB,c);
            if(c+1<NCH){
                stage_write(((c+1)&1)*BUFB);
                __syncthreads();
            }
        }
    }

    const float rs=(float)(1.0/sqrt(1.0+1e-3));
    float lsum=0.f, colsum=0.f;
    #pragma unroll
    for(int s=0;s<SMP;++s){
        const int b=b0+s;
        #pragma unroll
        for(int n=0;n<NT;++n){
            int col=n0+n*16+l15;
            float bi=bias[col];
            float gsc=0.f, bt=0.f;
            if constexpr(HASBN){ gsc=gamma[col]*rs; bt=beta[col]; }
            #pragma unroll
            for(int m=0;m<MT;++m){
                #pragma unroll
                for(int j=0;j<4;++j){
                    int p=m*16+lq*4+j;
                    if(p<NPOS){
                        float vx=acc[s][m][n][j]+bi;
                        if constexpr(HASBN) vx=fmaxf(fmaf(vx,gsc,bt),0.f);
                        size_t g=(size_t)b*NPOS+p;
                        if constexpr(OUTFMT==0){
                            out_f[g*OC+col]=vx;
                        } else if constexpr(OUTFMT==1){
                            ushort h=bf16_hi(vx);
                            ushort lo=bf16_hi(vx-bf16_tof(h));
                            out_pk[g*OC+col]=(uint)h | ((uint)lo<<16);
                        } else {
                            out_bf[g*OC+col]=bf16_hi(vx);
                        }
                        if constexpr(FUSE){
                            int id=ids[b*L+p];
                            float mm=(masks[b*L+p]>=1)?1.f:0.f;
                            float h=table[(size_t)id*64+col]*mm;
                            float df=h-vx;
                            lsum=fmaf(df,df,lsum);
                            colsum+=vx;
                        }
                    }
                }
            }
        }
    }

    if constexpr(FUSE){
        const int b=b0;
        float mc=0.f;
        for(int l=lane;l<L;l+=64) mc += (masks[b*L+l]>=1)?1.f:0.f;
        #pragma unroll
        for(int off=32;off;off>>=1) mc+=__shfl_xor(mc,off);
        colsum += __shfl_xor(colsum,16);
        colsum += __shfl_xor(colsum,32);
        if(lq==0) out_mean[b*64 + n0 + l15] = colsum/mc;
        #pragma unroll
        for(int off=32;off;off>>=1) lsum+=__shfl_xor(lsum,off);
        __syncthreads();
        float* red=(float*)sb;
        if(lane==0) red[wv]=lsum;
        __syncthreads();
        if(tid==0) atomicAdd(acc_g+0, red[0]+red[1]+red[2]+red[3]);
    }
}

__device__ inline int xswz(int row, int sl){ return (sl ^ (row&31) ^ ((row>>3)&7)) << 4; }

// ---------------------------------------------------------------------------
// xsq: Sum x^2 only. Hi plane only (32 KB LDS), 512 threads, 1 sample/block,
// 8 waves x 64 cols (2 passes of 2 col-chunks; each A-read feeds 2 MFMAs).
// __launch_bounds__(512,2): force total regs <= 128 for 4 waves/SIMD.
// ---------------------------------------------------------------------------
__global__ __launch_bounds__(512,2)
void xsq_k(const uint* __restrict__ in_pk,
           const ushort* __restrict__ wx,                        // EW3H
           const float* __restrict__ xbias,                      // e_b3
           float* __restrict__ acc_g)
{
    constexpr int NPOS=49, OW=7, MT=4;
    constexpr int ROWB=512;

    __shared__ ushort s_a[64*256];          // hi plane only = 32 KB
    char* sb=(char*)s_a;

    const int v=blockIdx.x;
    const int b=(v&7)*(B/8)+(v>>3);
    const int tid=threadIdx.x, lane=tid&63, wv=tid>>6;
    const int l15=lane&15, lq=lane>>4;

    #pragma unroll
    for(int t=0;t<4;++t){
        int idx=tid+t*512;
        int row=idx>>5, sl=idx&31;
        const uint* src=in_pk+((size_t)b*64+row)*256+sl*8;
        uint4 u0=*(const uint4*)src, u1=*(const uint4*)(src+4);
        const uint* p0=(const uint*)&u0;
        const uint* p1=(const uint*)&u1;
        ushort hh[8];
        #pragma unroll
        for(int j=0;j<4;++j){ hh[j]=(ushort)(p0[j]&0xffffu); hh[4+j]=(ushort)(p1[j]&0xffffu); }
        *(uint4*)(sb+row*ROWB+xswz(row,sl))=*(uint4*)hh;
    }
    __syncthreads();

    int arow[4][MT];
    #pragma unroll
    for(int kk=0;kk<4;++kk){
        const int ky=kk>>1, kx=kk&1;
        #pragma unroll
        for(int m=0;m<MT;++m){
            int p=m*16+l15;
            int py=p/OW, px=p-py*OW;
            arow[kk][m]= (p<NPOS) ? (py+ky)*8+(px+kx) : 0;
        }
    }

    float xs=0.f;
    #pragma unroll
    for(int cc=0;cc<2;++cc){
        f32x4 accx[MT][2];
        #pragma unroll
        for(int m=0;m<MT;++m){ accx[m][0]=(f32x4)0.0f; accx[m][1]=(f32x4)0.0f; }
        const int col0=wv*64+cc*32+l15;
        __builtin_amdgcn_s_setprio(1);
        #pragma unroll
        for(int kk=0;kk<4;++kk){
            #pragma unroll
            for(int ks=0;ks<8;++ks){
                short8v bx0=*(const short8v*)(wx+((size_t)kk*512+col0)*256+ks*32+lq*8);
                short8v bx1=*(const short8v*)(wx+((size_t)kk*512+col0+16)*256+ks*32+lq*8);
                const int slb=ks*4+lq;
                #pragma unroll
                for(int m=0;m<MT;++m){
                    int r=arow[kk][m];
                    short8v ah=*(const short8v*)(sb+r*ROWB+xswz(r,slb));
                    accx[m][0]=__builtin_amdgcn_mfma_f32_16x16x32_bf16(ah,bx0,accx[m][0],0,0,0);
                    accx[m][1]=__builtin_amdgcn_mfma_f32_16x16x32_bf16(ah,bx1,accx[m][1],0,0,0);
                }
            }
        }
        __builtin_amdgcn_s_setprio(0);
        #pragma unroll
        for(int n=0;n<2;++n){
            const float bi=xbias[col0+n*16];
            #pragma unroll
            for(int m=0;m<MT;++m){
                #pragma unroll
                for(int j=0;j<4;++j){
                    int p=m*16+lq*4+j;
                    if(p<NPOS){ float vv=accx[m][n][j]+bi; xs=fmaf(vv,vv,xs); }
                }
            }
        }
    }
    #pragma unroll
    for(int off=32;off;off>>=1) xs+=__shfl_xor(xs,off);

    __syncthreads();
    float* f=(float*)sb;
    if(lane==0) f[wv]=xs;
    __syncthreads();
    if(tid==0) atomicAdd(acc_g+1, f[0]+f[1]+f[2]+f[3]+f[4]+f[5]+f[6]+f[7]);
}

// ---------------------------------------------------------------------------
// dot: folded-codebook dots + argmin. Hi+lo (64 KB LDS), 512 threads, K-split.
// ---------------------------------------------------------------------------
__global__ __launch_bounds__(512)
void dot_k(const uint* __restrict__ in_pk,
           const ushort* __restrict__ w3bh, const ushort* __restrict__ w3bl,
           const float* __restrict__ cbn, const float* __restrict__ dotb,
           int* __restrict__ qidx, float* __restrict__ acc_g,
           int* __restrict__ cnt, int* __restrict__ wl)
{
    constexpr int NPOS=49, OW=7, MT=4;
    constexpr int ROWB=512;
    constexpr int PLB=64*ROWB;

    __shared__ ushort s_a[2*64*256];        // hi + lo = 64 KB
    char* sb=(char*)s_a;

    const int v=blockIdx.x;
    const int b=(v&7)*(B/8)+(v>>3);
    const int tid=threadIdx.x, lane=tid&63, wv=tid>>6;
    const int l15=lane&15, lq=lane>>4;

    #pragma unroll
    for(int t=0;t<4;++t){
        int idx=tid+t*512;
        int row=idx>>5, sl=idx&31;
        const uint* src=in_pk+((size_t)b*64+row)*256+sl*8;
        uint4 u0=*(const uint4*)src, u1=*(const uint4*)(src+4);
        const uint* p0=(const uint*)&u0;
        const uint* p1=(const uint*)&u1;
        ushort hh[8], ll[8];
        #pragma unroll
        for(int j=0;j<4;++j){ hh[j]=(ushort)(p0[j]&0xffffu); ll[j]=(ushort)(p0[j]>>16); }
        #pragma unroll
        for(int j=0;j<4;++j){ hh[4+j]=(ushort)(p1[j]&0xffffu); ll[4+j]=(ushort)(p1[j]>>16); }
        int boff=row*ROWB+xswz(row,sl);
        *(uint4*)(sb+boff)=*(uint4*)hh;
        *(uint4*)(sb+PLB+boff)=*(uint4*)ll;
    }
    __syncthreads();

    int arow[4][MT];
    #pragma unroll
    for(int kk=0;kk<4;++kk){
        const int ky=kk>>1, kx=kk&1;
        #pragma unroll
        for(int m=0;m<MT;++m){
            int p=m*16+l15;
            int py=p/OW, px=p-py*OW;
            arow[kk][m]= (p<NPOS) ? (py+ky)*8+(px+kx) : 0;
        }
    }

    const int cold=(wv&3)*16+l15;
    const int ks0=(wv>>2)*4;
    f32x4 accd[MT];
    #pragma unroll
    for(int m=0;m<MT;++m) accd[m]=(f32x4)0.0f;

    __builtin_amdgcn_s_setprio(1);
    #pragma unroll
    for(int kk=0;kk<4;++kk){
        #pragma unroll
        for(int kq2=0;kq2<4;++kq2){
            const int ks=ks0+kq2;
            size_t wdx=((size_t)kk*64+cold)*256+ks*32+lq*8;
            short8v bdh=*(const short8v*)(w3bh+wdx);
            short8v bdl=*(const short8v*)(w3bl+wdx);
            const int slb=ks*4+lq;
            #pragma unroll
            for(int m=0;m<MT;++m){
                int r=arow[kk][m];
                int off=r*ROWB+xswz(r,slb);
                short8v ah=*(const short8v*)(sb+off);
                short8v al=*(const short8v*)(sb+PLB+off);
                accd[m]=__builtin_amdgcn_mfma_f32_16x16x32_bf16(ah,bdh,accd[m],0,0,0);
                accd[m]=__builtin_amdgcn_mfma_f32_16x16x32_bf16(ah,bdl,accd[m],0,0,0);
                accd[m]=__builtin_amdgcn_mfma_f32_16x16x32_bf16(al,bdh,accd[m],0,0,0);
            }
        }
    }
    __builtin_amdgcn_s_setprio(0);

    __syncthreads();
    float* f=(float*)sb;
    if(wv>=4){
        float* dst=f+((wv-4)*64+lane)*16;
        #pragma unroll
        for(int m=0;m<MT;++m){
            #pragma unroll
            for(int j=0;j<4;++j) dst[m*4+j]=accd[m][j];
        }
    }
    __syncthreads();

    float* sd1=f+4096;
    int*   sk =(int*)(f+4096+256);
    float* sd2=f+4096+512;
    if(wv<4){
        const float* srcp=f+(wv*64+lane)*16;
        float cb=cbn[cold], db=dotb[cold];
        #pragma unroll
        for(int m=0;m<MT;++m){
            #pragma unroll
            for(int j=0;j<4;++j){
                int p=m*16+lq*4+j;
                float dtot=accd[m][j]+srcp[m*4+j];
                float d1=cb-2.f*(dtot+db);
                int   k1=cold;
                float d2=3.4e38f;
                #pragma unroll
                for(int off=1;off<16;off<<=1){
                    float od1=__shfl_xor(d1,off);
                    int   ok1=__shfl_xor(k1,off);
                    float od2=__shfl_xor(d2,off);
                    if(od1<d1 || (od1==d1 && ok1<k1)){ d2=fminf(d1,od2); d1=od1; k1=ok1; }
                    else                              { d2=fminf(d2,od1); }
                }
                if(l15==0 && p<NPOS){ sd1[p*4+wv]=d1; sk[p*4+wv]=k1; sd2[p*4+wv]=d2; }
            }
        }
    }
    __syncthreads();

    {
        float lsum=0.f;
        if(tid<NPOS){
            float d1=sd1[tid*4+0]; int k1=sk[tid*4+0]; float d2=sd2[tid*4+0];
            #pragma unroll
            for(int w=1;w<4;++w){
                float D1=sd1[tid*4+w]; int K1=sk[tid*4+w]; float D2=sd2[tid*4+w];
                if(D1<d1){ d2=fminf(d1,D2); d1=D1; k1=K1; }
                else     { d2=fminf(d2,D1); }
            }
            qidx[b*49+tid]=k1;
            if(d2-d1<=MARGIN){ int t=atomicAdd(cnt,1); wl[t]=b*49+tid; }
            lsum=d1;
        }
        if(tid<64){
            #pragma unroll
            for(int off=32;off;off>>=1) lsum+=__shfl_xor(lsum,off);
            if(tid==0) atomicAdd(acc_g+1, lsum);
        }
    }
}

// ---------------------------------------------------------------------------
// deconv1 as gather-sum over BW1.
// ---------------------------------------------------------------------------
__global__ __launch_bounds__(256)
void dgather_k(const int* __restrict__ qidx, const float* __restrict__ bw1,
               const float* __restrict__ b1, const float* __restrict__ g1s,
               const float* __restrict__ be1, ushort* __restrict__ G1)
{
    const int b=blockIdx.x, tid=threadIdx.x;
    const int pg=tid>>2, og=(tid&3)*64;
    const int py=pg>>3, px=pg&7;

    float a[64];
    #pragma unroll
    for(int j=0;j<64;++j) a[j]=0.f;

    #pragma unroll
    for(int tap=0;tap<4;++tap){
        int iy=py+(tap>>1)-1, ix=px+(tap&1)-1;
        if((unsigned)iy<7u && (unsigned)ix<7u){
            int kq=qidx[b*49+iy*7+ix];
            const float4* src=(const float4*)(bw1+((size_t)(tap*64+kq))*256+og);
            #pragma unroll
            for(int j=0;j<16;++j){
                float4 vv=src[j];
                a[4*j+0]+=vv.x; a[4*j+1]+=vv.y; a[4*j+2]+=vv.z; a[4*j+3]+=vv.w;
            }
        }
    }
    const float rs=(float)(1.0/sqrt(1.0+1e-3));
    #pragma unroll
    for(int j=0;j<64;++j){
        int col=og+j;
        float vv=a[j]+b1[col];
        vv=fmaxf(fmaf(vv, g1s[col]*rs, be1[col]), 0.f);
        G1[((size_t)b*64+pg)*256+col]=bf16_hi(vv);
    }
}

// ---------------------------------------------------------------------------
// f64 re-verification of flagged rows (full receptive field from scratch).
// Round-16 byte-identical body; grid 8192.
// ---------------------------------------------------------------------------
__global__ __launch_bounds__(256)
void recompute_k(const int* __restrict__ wl, const int* __restrict__ cnt,
                 const int* __restrict__ ids, const int* __restrict__ masks,
                 const float* __restrict__ table, const float* __restrict__ book,
                 const float* __restrict__ e_w1, const float* __restrict__ e_b1,
                 const float* __restrict__ e_g1, const float* __restrict__ e_be1,
                 const float* __restrict__ e_w2, const float* __restrict__ e_b2,
                 const float* __restrict__ e_g2, const float* __restrict__ e_be2,
                 const float* __restrict__ e_w3, const float* __restrict__ e_b3,
                 int* __restrict__ qidx)
{
    __shared__ double s_h[16*64];
    __shared__ double s_a1[9*128];
    __shared__ double s_a2[4*256];
    __shared__ double s_x[512];
    __shared__ double s_d[256];

    const int tid = threadIdx.x;
    const double rs = 1.0 / sqrt(1.0 + 1e-3);
    const int n = *cnt;

    for (int wi = blockIdx.x; wi < n; wi += gridDim.x) {
        const int row = wl[wi];
        const int b = row / 49, p = row % 49;
        const int py = p / 7, px = p % 7;

        for (int i = tid; i < 16*64; i += 256) {
            int cell = i >> 6, d = i & 63;
            int l = (py + (cell >> 2)) * 10 + (px + (cell & 3));
            int id = ids[b*100 + l];
            double m = (masks[b*100 + l] >= 1) ? 1.0 : 0.0;
            s_h[i] = (double)table[(size_t)id*64 + d] * m;
        }
        __syncthreads();

        for (int i = tid; i < 9*128; i += 256) {
            int cell = i >> 7, oc = i & 127;
            int ry = cell / 3, rx = cell % 3;
            double s = 0.0;
            #pragma unroll
            for (int kk = 0; kk < 4; ++kk) {
                int icell = (ry + (kk>>1))*4 + (rx + (kk&1));
                const double* hh = s_h + icell*64;
                const float* ww = e_w1 + (kk*64)*128 + oc;
                for (int ic = 0; ic < 64; ++ic)
                    s = fma(hh[ic], (double)ww[ic*128], s);
            }
            s += (double)e_b1[oc];
            s = s * ((double)e_g1[oc] * rs) + (double)e_be1[oc];
            s_a1[i] = s > 0.0 ? s : 0.0;
        }
        __syncthreads();

        for (int i = tid; i < 4*256; i += 256) {
            int cell = i >> 8, oc = i & 255;
            int qy = cell >> 1, qx = cell & 1;
            double s = 0.0;
            #pragma unroll
            for (int kk = 0; kk < 4; ++kk) {
                int icell = (qy + (kk>>1))*3 + (qx + (kk&1));
                const double* aa = s_a1 + icell*128;
                const float* ww = e_w2 + (kk*128)*256 + oc;
                for (int ic = 0; ic < 128; ++ic)
                    s = fma(aa[ic], (double)ww[ic*256], s);
            }
            s += (double)e_b2[oc];
            s = s * ((double)e_g2[oc] * rs) + (double)e_be2[oc];
            s_a2[i] = s > 0.0 ? s : 0.0;
        }
        __syncthreads();

        for (int i = tid; i < 512; i += 256) {
            double s = 0.0;
            #pragma unroll
            for (int kk = 0; kk < 4; ++kk) {
                const double* aa = s_a2 + kk*256;
                const float* ww = e_w3 + (kk*256)*512 + i;
                for (int ic = 0; ic < 256; ++ic)
                    s = fma(aa[ic], (double)ww[ic*512], s);
            }
            s_x[i] = s + (double)e_b3[i];
        }
        __syncthreads();

        {
            int k = tid & 63, seg = tid >> 6;
            const float* cr = book + k*512 + seg*128;
            const double* xr = s_x + seg*128;
            double s = 0.0;
            for (int c = 0; c < 128; ++c) {
                double dd = xr[c] - (double)cr[c];
                s = fma(dd, dd, s);
            }
            s_d[seg*64 + k] = s;
        }
        __syncthreads();

        if (tid < 64) {
            double dv = s_d[tid] + s_d[64+tid] + s_d[128+tid] + s_d[192+tid];
            int kk2 = tid;
            #pragma unroll
            for (int off = 32; off > 0; off >>= 1) {
                double od = __shfl_xor(dv, off);
                int    ok = __shfl_xor(kk2, off);
                if (od < dv || (od == dv && ok < kk2)) { dv = od; kk2 = ok; }
            }
            if (tid == 0) qidx[row] = kk2;
        }
        __syncthreads();
    }
}

__global__ void loss_k(const float* __restrict__ acc, float* __restrict__ out_loss)
{
    float l1 = acc[0] / 13107200.f;
    float l2 = acc[1] / 51380224.f;
    out_loss[0] = l1 + l2 + 0.25f * l2;
}

// ---------------------------------------------------------------------------
extern "C" void kernel_launch(void* const* d_in, const int* in_sizes, int n_in,
                              void* d_out, int out_size, void* d_ws, size_t ws_size,
                              hipStream_t stream)
{
    const int*   ids   = (const int*)d_in[0];
    const int*   masks = (const int*)d_in[1];
    const float* table = (const float*)d_in[2];
    const float* book  = (const float*)d_in[3];
    const float* e_w1  = (const float*)d_in[4];
    const float* e_b1  = (const float*)d_in[5];
    const float* e_g1  = (const float*)d_in[6];
    const float* e_be1 = (const float*)d_in[7];
    const float* e_w2  = (const float*)d_in[8];
    const float* e_b2  = (const float*)d_in[9];
    const float* e_g2  = (const float*)d_in[10];
    const float* e_be2 = (const float*)d_in[11];
    const float* e_w3  = (const float*)d_in[12];
    const float* e_b3  = (const float*)d_in[13];
    const float* d_w1  = (const float*)d_in[14];
    const float* d_b1  = (const float*)d_in[15];
    const float* d_g1  = (const float*)d_in[16];
    const float* d_be1 = (const float*)d_in[17];
    const float* d_w2  = (const float*)d_in[18];
    const float* d_b2  = (const float*)d_in[19];
    const float* d_g2  = (const float*)d_in[20];
    const float* d_be2 = (const float*)d_in[21];
    const float* d_w3  = (const float*)d_in[22];
    const float* d_b3  = (const float*)d_in[23];

    float*  ws  = (float*)d_ws;
    uint*   A1P = (uint*)(ws + R0_OFF);   // [B*81*128] u32 hi|lo
    uint*   A2P = (uint*)(ws + R1_OFF);   // [B*64*256] u32 hi|lo
    ushort* G1  = (ushort*)(ws + R1_OFF); // [B*64*256] bf16 (after dot/xsq)
    ushort* G2  = (ushort*)(ws + R0_OFF); // [B*81*128] bf16 (after conv2)
    int*    IDX = (int*)(ws + IDX_OFF);
    float*  CBN = ws + CBN_OFF;
    int*    CNT = (int*)(ws + CNT_OFF);
    float*  ACC = ws + ACC_OFF;
    int*    WL  = (int*)(ws + WL_OFF);
    ushort* WB  = (ushort*)(ws + WB_OFF);
    float*  BW1 = ws + BW1_OFF;
    float*  DOTB= ws + DOTB_OFF;

    float* out_mean = (float*)d_out;
    float* out_vqx  = (float*)d_out + (size_t)B * 64;
    float* out_loss = (float*)d_out + (size_t)B * 64 + (size_t)B * L * 64;

    prep_k<<<1, 256, 0, stream>>>(book, e_b3, CBN, DOTB, ACC, CNT);
    wprep_k<<<512, 256, 0, stream>>>(e_w1, e_w2, e_w3, d_w2, d_w3, WB);
    w3b_k<<<256, 256, 0, stream>>>(e_w3, book, WB);
    bw1_k<<<256, 256, 0, stream>>>(d_w1, book, BW1);

    // encoder (split-bf16) — round-10 configs
    sconv_k<10,10, 64,128,0,1,true ,true ,1, 64,6,1,false,1,true ><<<B,   256,0,stream>>>(
        nullptr, nullptr, ids, masks, table,
        WB+EW1H, WB+EW1L, e_b1, e_g1, e_be1, nullptr, A1P, nullptr, nullptr, nullptr);
    sconv_k< 9, 9,128,256,0,3,true ,true ,2, 64,4,1,false,1,true ><<<B*2, 256,0,stream>>>(
        A1P, nullptr, nullptr, nullptr, nullptr,
        WB+EW2H, WB+EW2L, e_b2, e_g2, e_be2, nullptr, A2P, nullptr, nullptr, nullptr);

    // Sum x^2 (lean, hi-only, forced 2 blocks/CU) + folded-codebook dots/argmin
    xsq_k<<<B, 512, 0, stream>>>(A2P, WB+EW3H, e_b3, ACC);
    dot_k<<<B, 512, 0, stream>>>(A2P, WB+W3BH, WB+W3BL, CBN, DOTB, IDX, ACC, CNT, WL);

    // f64 re-verify flagged rows (round-16 kernel, grid 8192)
    recompute_k<<<8192, 256, 0, stream>>>(WL, CNT, ids, masks, table, book,
                                          e_w1, e_b1, e_g1, e_be1,
                                          e_w2, e_b2, e_g2, e_be2,
                                          e_w3, e_b3, IDX);

    // decoder: deconv1 = gather-sum; deconv2/3 = bf16 MFMA convs (round-10)
    dgather_k<<<B, 256, 0, stream>>>(IDX, BW1, d_b1, d_g1, d_be1, G1);
    sconv_k< 8, 8,256,128,1,4,true ,false,1, 64,6,2,false,1,true ><<<B,   256,0,stream>>>(
        nullptr, G1, nullptr, nullptr, nullptr,
        WB+DW2H, nullptr, d_b2, d_g2, d_be2, nullptr, nullptr, G2, nullptr, nullptr);
    sconv_k< 9, 9,128, 64,1,4,false,false,1, 64,7,0,true ,1,true ><<<B,   256,0,stream>>>(
        nullptr, G2, ids, masks, table,
        WB+DW3H, nullptr, d_b3, nullptr, nullptr, out_vqx, nullptr, nullptr, out_mean, ACC);

    loss_k<<<1, 1, 0, stream>>>(ACC, out_loss);
}